// Round 3
// baseline (3046.378 us; speedup 1.0000x reference)
//
#include <hip/hip_runtime.h>

typedef unsigned int uint32;
typedef __bf16 bf16x8 __attribute__((ext_vector_type(8)));
typedef float f32x4 __attribute__((ext_vector_type(4)));

constexpr int N_C = 100000, N_T = 5000, E_EDGES = 2000000;
constexpr int D_C = 1024, D_T = 1280, H = 64, H2 = 32, NL = 3;
constexpr int NBC = (N_C + 127) / 128;   // 782 MFMA blocks for compounds
constexpr int NBT = (N_T + 127) / 128;   // 40

// ---- CSR build (two-level counting sort, zero atomic-with-return) ----
constexpr int CCH = 200;                  // chunks per graph
constexpr int CHE = E_EDGES / CCH;        // 10000 edges per chunk (exact)
constexpr int SH_T = 4,  FB_T = 16;       // target: bucket = dst>>4, 16 fine bins
constexpr int SH_C = 8,  FB_C = 256;      // compound: bucket = dst>>8, 256 fine bins
constexpr int NB_T_B = (N_T + FB_T - 1) / FB_T;   // 313 buckets
constexpr int NB_C_B = (N_C + FB_C - 1) / FB_C;   // 391 buckets
constexpr int NB_TOT = NB_T_B + NB_C_B;           // 704
// packed col entry: target (dst<<17)|src  (13+17 bits); compound (dst<<13)|src (17+13)
constexpr int PB_T = 17; constexpr uint32 PM_T = 0x1FFFFu;
constexpr int PB_C = 13; constexpr uint32 PM_C = 0x1FFFu;

__device__ inline unsigned short f2bf(float f) {
  uint32 u = __float_as_uint(f);
  u += 0x7fffu + ((u >> 16) & 1u);          // round-to-nearest-even
  return (unsigned short)(u >> 16);
}

// ---------------- prep: weight transposes + zero bucket totals (1 node)
__global__ __launch_bounds__(256) void prep_kernel(
    const float* __restrict__ Wc, const float* __restrict__ Wt,
    const float* __restrict__ Wl, const float* __restrict__ Wr,
    __bf16* __restrict__ WcT, __bf16* __restrict__ WtT, __bf16* __restrict__ WsT,
    int* __restrict__ T)
{
  int t = blockIdx.x * 256 + threadIdx.x;
  const int Z = NB_TOT;
  const int A = D_C * 64;
  const int B = D_T * 64;
  const int S = 6 * 64 * 64;
  if (t < Z) { T[t] = 0; return; }
  t -= Z;
  if (t < A) { int n = t & 63, k = t >> 6; WcT[(size_t)n * D_C + k] = (__bf16)Wc[(size_t)k * 64 + n]; return; }
  t -= A;
  if (t < B) { int n = t & 63, k = t >> 6; WtT[(size_t)n * D_T + k] = (__bf16)Wt[(size_t)k * 64 + n]; return; }
  t -= B;
  if (t < S) {
    int i = t >> 12;
    int r = t & 4095; int n = r & 63, k = r >> 6;
    const float* src = (i < 3) ? (Wl + (size_t)i * 4096) : (Wr + (size_t)(i - 3) * 4096);
    WsT[(size_t)i * 4096 + (size_t)n * 64 + k] = (__bf16)src[(size_t)k * 64 + n];
  }
}

// ---------------- MFMA projection body: y = relu(x @ W + b)
template<int K>
__device__ __forceinline__ void projM_body(
    const float* __restrict__ x, const __bf16* __restrict__ WT,
    const float* __restrict__ b, float* __restrict__ y,
    unsigned short* __restrict__ yh, int n, int bidx)
{
  int w = threadIdx.x >> 6, l = threadIdx.x & 63;
  int lm = l & 15, lk = l >> 4;
  int base = bidx * 128 + w * 32;
  int r0 = base + lm;      if (r0 >= n) r0 = n - 1;
  int r1 = base + 16 + lm; if (r1 >= n) r1 = n - 1;
  const float* xp0 = x + (size_t)r0 * K + lk * 8;
  const float* xp1 = x + (size_t)r1 * K + lk * 8;
  const __bf16* wp = WT + (size_t)lm * K + lk * 8;

  f32x4 acc0[4] = {{0,0,0,0},{0,0,0,0},{0,0,0,0},{0,0,0,0}};
  f32x4 acc1[4] = {{0,0,0,0},{0,0,0,0},{0,0,0,0},{0,0,0,0}};

  float4 p00 = *(const float4*)(xp0);
  float4 p01 = *(const float4*)(xp0 + 4);
  float4 p10 = *(const float4*)(xp1);
  float4 p11 = *(const float4*)(xp1 + 4);

  for (int k0 = 0; k0 < K; k0 += 32) {
    bf16x8 a0, a1;
    a0[0]=(__bf16)p00.x; a0[1]=(__bf16)p00.y; a0[2]=(__bf16)p00.z; a0[3]=(__bf16)p00.w;
    a0[4]=(__bf16)p01.x; a0[5]=(__bf16)p01.y; a0[6]=(__bf16)p01.z; a0[7]=(__bf16)p01.w;
    a1[0]=(__bf16)p10.x; a1[1]=(__bf16)p10.y; a1[2]=(__bf16)p10.z; a1[3]=(__bf16)p10.w;
    a1[4]=(__bf16)p11.x; a1[5]=(__bf16)p11.y; a1[6]=(__bf16)p11.z; a1[7]=(__bf16)p11.w;
    if (k0 + 32 < K) {
      p00 = *(const float4*)(xp0 + k0 + 32);
      p01 = *(const float4*)(xp0 + k0 + 36);
      p10 = *(const float4*)(xp1 + k0 + 32);
      p11 = *(const float4*)(xp1 + k0 + 36);
    }
#pragma unroll
    for (int fn = 0; fn < 4; ++fn) {
      bf16x8 bv = *(const bf16x8*)(wp + (size_t)fn * 16 * K + k0);
      acc0[fn] = __builtin_amdgcn_mfma_f32_16x16x32_bf16(a0, bv, acc0[fn], 0, 0, 0);
      acc1[fn] = __builtin_amdgcn_mfma_f32_16x16x32_bf16(a1, bv, acc1[fn], 0, 0, 0);
    }
  }

#pragma unroll
  for (int fn = 0; fn < 4; ++fn) {
    int col = fn * 16 + lm;
    float bb = b[col];
#pragma unroll
    for (int reg = 0; reg < 4; ++reg) {
      int row = base + lk * 4 + reg;
      if (row < n) {
        float o = fmaxf(acc0[fn][reg] + bb, 0.f);
        y[(size_t)row * 64 + col] = o;
        yh[(size_t)row * 64 + col] = f2bf(o);
      }
      row = base + 16 + lk * 4 + reg;
      if (row < n) {
        float o = fmaxf(acc1[fn][reg] + bb, 0.f);
        y[(size_t)row * 64 + col] = o;
        yh[(size_t)row * 64 + col] = f2bf(o);
      }
    }
  }
}

__global__ __launch_bounds__(256) void proj_kernel(
    const float* __restrict__ x_comp, const __bf16* __restrict__ WcT,
    const float* __restrict__ bc, float* __restrict__ xc, unsigned short* __restrict__ xch,
    const float* __restrict__ x_tgt, const __bf16* __restrict__ WtT,
    const float* __restrict__ bt, float* __restrict__ xt, unsigned short* __restrict__ xth)
{
  if (blockIdx.x < NBC) projM_body<D_C>(x_comp, WcT, bc, xc, xch, N_C, blockIdx.x);
  else                  projM_body<D_T>(x_tgt, WtT, bt, xt, xth, N_T, blockIdx.x - NBC);
}

// ---------------- csr1: per-chunk coarse-bucket histograms (LDS)
__global__ __launch_bounds__(256) void csr1_kernel(
    const int* __restrict__ dst_ct, const int* __restrict__ dst_tc,
    int* __restrict__ h1, int* __restrict__ T)
{
  __shared__ int hist[NB_C_B];
  int graph = (blockIdx.x >= CCH) ? 1 : 0;
  int chunk = graph ? (blockIdx.x - CCH) : blockIdx.x;
  const int* dst = graph ? dst_tc : dst_ct;
  int NB = graph ? NB_C_B : NB_T_B;
  int SH = graph ? SH_C : SH_T;
  for (int i = threadIdx.x; i < NB; i += 256) hist[i] = 0;
  __syncthreads();
  int e0 = chunk * CHE;
  for (int i = threadIdx.x; i < CHE; i += 256)
    atomicAdd(&hist[dst[e0 + i] >> SH], 1);
  __syncthreads();
  int* h1g = h1 + (graph ? (size_t)NB_T_B * CCH : 0);
  int* Tg  = T + (graph ? NB_T_B : 0);
  for (int i = threadIdx.x; i < NB; i += 256) {
    int v = hist[i];
    h1g[(size_t)i * CCH + chunk] = v;
    if (v) atomicAdd(&Tg[i], v);       // fire-and-forget
  }
}

// ---------------- csr2: per-bucket bases + chunk-prefix of h1 row
__global__ __launch_bounds__(256) void csr2_kernel(
    const int* __restrict__ h1, const int* __restrict__ T, int* __restrict__ b1)
{
  __shared__ int sh[256];
  __shared__ int loc2[512];
  int b = blockIdx.x;
  int graph = (b >= NB_T_B) ? 1 : 0;
  int nb = graph ? NB_C_B : NB_T_B;
  int base = graph ? NB_T_B : 0;
  int bl = b - base;
  int tid = threadIdx.x;
  int v0 = (2 * tid     < nb) ? T[base + 2 * tid]     : 0;
  int v1 = (2 * tid + 1 < nb) ? T[base + 2 * tid + 1] : 0;
  int t = v0 + v1;
  sh[tid] = t;
  __syncthreads();
  for (int off = 1; off < 256; off <<= 1) {
    int xv = (tid >= off) ? sh[tid - off] : 0;
    __syncthreads(); sh[tid] += xv; __syncthreads();
  }
  int excl = sh[tid] - t;
  loc2[2 * tid] = excl;
  loc2[2 * tid + 1] = excl + v0;
  __syncthreads();
  int B = loc2[bl];
  const int* row = h1 + (graph ? (size_t)NB_T_B * CCH : 0) + (size_t)bl * CCH;
  int hv = (tid < CCH) ? row[tid] : 0;
  sh[tid] = hv;
  __syncthreads();
  for (int off = 1; off < 256; off <<= 1) {
    int xv = (tid >= off) ? sh[tid - off] : 0;
    __syncthreads(); sh[tid] += xv; __syncthreads();
  }
  int e2 = sh[tid] - hv;
  if (tid < CCH) {
    int* b1g = b1 + (graph ? (size_t)NB_T_B * CCH : 0) + (size_t)bl * CCH;
    b1g[tid] = B + e2;
  }
}

// ---------------- csr3: scatter edges into bucket-major temp (full-dst pack)
__global__ __launch_bounds__(256) void csr3_kernel(
    const int* __restrict__ src_ct, const int* __restrict__ dst_ct,
    const int* __restrict__ src_tc, const int* __restrict__ dst_tc,
    const int* __restrict__ b1, uint32* __restrict__ packT_t, uint32* __restrict__ packT_c)
{
  __shared__ int cur[NB_C_B];
  int graph = (blockIdx.x >= CCH) ? 1 : 0;
  int chunk = graph ? (blockIdx.x - CCH) : blockIdx.x;
  const int* dst = graph ? dst_tc : dst_ct;
  const int* src = graph ? src_tc : src_ct;
  uint32* packT = graph ? packT_c : packT_t;
  int NB = graph ? NB_C_B : NB_T_B;
  int SH = graph ? SH_C : SH_T;
  int SB = graph ? PB_C : PB_T;
  const int* b1g = b1 + (graph ? (size_t)NB_T_B * CCH : 0);
  for (int i = threadIdx.x; i < NB; i += 256) cur[i] = b1g[(size_t)i * CCH + chunk];
  __syncthreads();
  int e0 = chunk * CHE;
  for (int i = threadIdx.x; i < CHE; i += 256) {
    int d = dst[e0 + i], s = src[e0 + i];
    int p = atomicAdd(&cur[d >> SH], 1);   // LDS atomic
    packT[p] = ((uint32)d << SB) | (uint32)s;
  }
}

// ---------------- csr4: per-bucket fine counting sort -> rowptr + packed col
__global__ __launch_bounds__(256) void csr4_kernel(
    const int* __restrict__ b1, const uint32* __restrict__ packT_t,
    const uint32* __restrict__ packT_c,
    int* __restrict__ rowptr_t, uint32* __restrict__ col_ct,
    int* __restrict__ rowptr_c, uint32* __restrict__ col_tc)
{
  __shared__ int hist[FB_C];
  __shared__ int exc[256];
  int b = blockIdx.x;
  int graph = (b >= NB_T_B) ? 1 : 0;
  int bl = graph ? (b - NB_T_B) : b;
  int nb = graph ? NB_C_B : NB_T_B;
  int FB = graph ? FB_C : FB_T;
  int SB = graph ? PB_C : PB_T;
  uint32 FMM = (uint32)(FB - 1);
  int N  = graph ? N_C : N_T;
  const uint32* packT = graph ? packT_c : packT_t;
  int* rowptr = graph ? rowptr_c : rowptr_t;
  uint32* col = graph ? col_tc : col_ct;
  const int* b1g = b1 + (graph ? (size_t)NB_T_B * CCH : 0);
  int seg0 = b1g[(size_t)bl * CCH];
  int seg1 = (bl + 1 < nb) ? b1g[(size_t)(bl + 1) * CCH] : E_EDGES;
  int tid = threadIdx.x;
  if (tid < FB) hist[tid] = 0;
  __syncthreads();
  for (int i = seg0 + tid; i < seg1; i += 256)
    atomicAdd(&hist[(packT[i] >> SB) & FMM], 1);
  __syncthreads();
  int hv = (tid < FB) ? hist[tid] : 0;
  exc[tid] = hv;
  __syncthreads();
  for (int off = 1; off < 256; off <<= 1) {
    int xv = (tid >= off) ? exc[tid - off] : 0;
    __syncthreads(); exc[tid] += xv; __syncthreads();
  }
  int excl = exc[tid] - hv;
  __syncthreads();
  if (tid < FB) {
    int gbin = bl * FB + tid;
    if (gbin <= N) rowptr[gbin] = seg0 + excl;
    hist[tid] = seg0 + excl;
  }
  __syncthreads();
  for (int i = seg0 + tid; i < seg1; i += 256) {
    uint32 pk = packT[i];
    int p = atomicAdd(&hist[(pk >> SB) & FMM], 1);
    col[p] = pk;                                  // full (dst<<SB)|src
  }
}

// ---------------- one node per layer
// blocks [0,N_T): target SAGE (unchanged numerics, unroll-8 MLP)
// blocks [N_T, N_T+NBC): compound edge-flat LDS-atomic agg + MFMA combine
__global__ __launch_bounds__(256) void layer_kernel(
    const unsigned short* __restrict__ xch_a, const float* __restrict__ xt_a,
    const int* __restrict__ rowptr_t, const uint32* __restrict__ col_ct,
    const float* __restrict__ Wl_t, const float* __restrict__ bl_t, const float* __restrict__ Wr_t,
    float* __restrict__ xt_n, unsigned short* __restrict__ xth_n,
    const unsigned short* __restrict__ xth_a, const int* __restrict__ rowptr_c,
    const uint32* __restrict__ col_tc,
    const __bf16* __restrict__ WlT, const __bf16* __restrict__ WrT,
    const float* __restrict__ bl_c, const float* __restrict__ xc_a,
    float* __restrict__ xc_n, unsigned short* __restrict__ xch_n)
{
  __shared__ __align__(16) float smem[128 * 68];   // 34.8 KB (compound sums; target aliases)
  float (*part)[64]  = (float(*)[64])smem;
  float (*opart)[64] = (float(*)[64])(smem + 256);

  int l = threadIdx.x & 63, w = threadIdx.x >> 6;
  int d = l & 31, half = l >> 5;

  if (blockIdx.x < N_T) {
    // -------- target-side SAGE (one block per row; 8 gathers in flight per half)
    int r = blockIdx.x;
    int start = rowptr_t[r], end = rowptr_t[r + 1];
    int deg = end - start;
    int quarter = (deg + 3) >> 2;
    int js = start + w * quarter;
    int je = js + quarter; if (je > end) je = end;
    const uint32* xp = (const uint32*)xch_a;
    float a0 = 0.f, a1 = 0.f;
    int j = js + half;
    for (; j + 14 < je; j += 16) {
      uint32 c0 = col_ct[j]      & PM_T, c1 = col_ct[j + 2]  & PM_T;
      uint32 c2 = col_ct[j + 4]  & PM_T, c3 = col_ct[j + 6]  & PM_T;
      uint32 c4 = col_ct[j + 8]  & PM_T, c5 = col_ct[j + 10] & PM_T;
      uint32 c6 = col_ct[j + 12] & PM_T, c7 = col_ct[j + 14] & PM_T;
      uint32 v0 = xp[(size_t)c0 * 32 + d];
      uint32 v1 = xp[(size_t)c1 * 32 + d];
      uint32 v2 = xp[(size_t)c2 * 32 + d];
      uint32 v3 = xp[(size_t)c3 * 32 + d];
      uint32 v4 = xp[(size_t)c4 * 32 + d];
      uint32 v5 = xp[(size_t)c5 * 32 + d];
      uint32 v6 = xp[(size_t)c6 * 32 + d];
      uint32 v7 = xp[(size_t)c7 * 32 + d];
      a0 += __uint_as_float(v0 << 16); a1 += __uint_as_float(v0 & 0xffff0000u);
      a0 += __uint_as_float(v1 << 16); a1 += __uint_as_float(v1 & 0xffff0000u);
      a0 += __uint_as_float(v2 << 16); a1 += __uint_as_float(v2 & 0xffff0000u);
      a0 += __uint_as_float(v3 << 16); a1 += __uint_as_float(v3 & 0xffff0000u);
      a0 += __uint_as_float(v4 << 16); a1 += __uint_as_float(v4 & 0xffff0000u);
      a0 += __uint_as_float(v5 << 16); a1 += __uint_as_float(v5 & 0xffff0000u);
      a0 += __uint_as_float(v6 << 16); a1 += __uint_as_float(v6 & 0xffff0000u);
      a0 += __uint_as_float(v7 << 16); a1 += __uint_as_float(v7 & 0xffff0000u);
    }
    for (; j < je; j += 2) {
      uint32 v = xp[(size_t)(col_ct[j] & PM_T) * 32 + d];
      a0 += __uint_as_float(v << 16); a1 += __uint_as_float(v & 0xffff0000u);
    }
    a0 += __shfl_xor(a0, 32, 64);
    a1 += __shfl_xor(a1, 32, 64);
    if (half == 0) *(float2*)&part[w][2 * d] = make_float2(a0, a1);
    __syncthreads();
    float m = (part[0][l] + part[1][l] + part[2][l] + part[3][l])
              * ((deg > 0) ? (1.0f / (float)deg) : 0.f);
    float xv = xt_a[(size_t)r * 64 + l];
    float o = 0.f;
    int k0 = w * 16;
#pragma unroll
    for (int kk = 0; kk < 16; ++kk) {
      int k = k0 + kk;
      float mk = __uint_as_float(__builtin_amdgcn_readlane(__float_as_uint(m), k));
      float xk = __uint_as_float(__builtin_amdgcn_readlane(__float_as_uint(xv), k));
      o = fmaf(mk, Wl_t[k * 64 + l], o);
      o = fmaf(xk, Wr_t[k * 64 + l], o);
    }
    opart[w][l] = o;
    __syncthreads();
    if (w == 0) {
      float oo = opart[0][l] + opart[1][l] + opart[2][l] + opart[3][l] + bl_t[l];
      float res = fmaxf(oo, 0.f) + xv;
      xt_n[(size_t)r * 64 + l] = res;
      xth_n[(size_t)r * 64 + l] = f2bf(res);
    }
    return;
  }

  // -------- compound side: edge-flat LDS-atomic aggregation, then MFMA combine
  int bblk = blockIdx.x - N_T;
  int B0 = bblk * 128;
  int r0w = B0 + w * 32;

  // zero own 32-row region (no barrier needed: per-wave ownership, DS in-order)
  float* srow = smem + (size_t)(w * 32) * 68;
  for (int i = l; i < 32 * 68; i += 64) srow[i] = 0.f;

  int wsI = r0w;        if (wsI > N_C) wsI = N_C;
  int weI = r0w + 32;   if (weI > N_C) weI = N_C;
  int ws = rowptr_c[wsI], we = rowptr_c[weI];
  const uint32* xp = (const uint32*)xth_a;

  int e = ws + half;
  for (; e + 14 < we; e += 16) {
    uint32 pk0 = col_tc[e],      pk1 = col_tc[e + 2];
    uint32 pk2 = col_tc[e + 4],  pk3 = col_tc[e + 6];
    uint32 pk4 = col_tc[e + 8],  pk5 = col_tc[e + 10];
    uint32 pk6 = col_tc[e + 12], pk7 = col_tc[e + 14];
    uint32 v0 = xp[(size_t)(pk0 & PM_C) * 32 + d];
    uint32 v1 = xp[(size_t)(pk1 & PM_C) * 32 + d];
    uint32 v2 = xp[(size_t)(pk2 & PM_C) * 32 + d];
    uint32 v3 = xp[(size_t)(pk3 & PM_C) * 32 + d];
    uint32 v4 = xp[(size_t)(pk4 & PM_C) * 32 + d];
    uint32 v5 = xp[(size_t)(pk5 & PM_C) * 32 + d];
    uint32 v6 = xp[(size_t)(pk6 & PM_C) * 32 + d];
    uint32 v7 = xp[(size_t)(pk7 & PM_C) * 32 + d];
    float* a0p = smem + (size_t)((pk0 >> PB_C) - B0) * 68 + 2 * d;
    float* a1p = smem + (size_t)((pk1 >> PB_C) - B0) * 68 + 2 * d;
    float* a2p = smem + (size_t)((pk2 >> PB_C) - B0) * 68 + 2 * d;
    float* a3p = smem + (size_t)((pk3 >> PB_C) - B0) * 68 + 2 * d;
    float* a4p = smem + (size_t)((pk4 >> PB_C) - B0) * 68 + 2 * d;
    float* a5p = smem + (size_t)((pk5 >> PB_C) - B0) * 68 + 2 * d;
    float* a6p = smem + (size_t)((pk6 >> PB_C) - B0) * 68 + 2 * d;
    float* a7p = smem + (size_t)((pk7 >> PB_C) - B0) * 68 + 2 * d;
    atomicAdd(a0p, __uint_as_float(v0 << 16)); atomicAdd(a0p + 1, __uint_as_float(v0 & 0xffff0000u));
    atomicAdd(a1p, __uint_as_float(v1 << 16)); atomicAdd(a1p + 1, __uint_as_float(v1 & 0xffff0000u));
    atomicAdd(a2p, __uint_as_float(v2 << 16)); atomicAdd(a2p + 1, __uint_as_float(v2 & 0xffff0000u));
    atomicAdd(a3p, __uint_as_float(v3 << 16)); atomicAdd(a3p + 1, __uint_as_float(v3 & 0xffff0000u));
    atomicAdd(a4p, __uint_as_float(v4 << 16)); atomicAdd(a4p + 1, __uint_as_float(v4 & 0xffff0000u));
    atomicAdd(a5p, __uint_as_float(v5 << 16)); atomicAdd(a5p + 1, __uint_as_float(v5 & 0xffff0000u));
    atomicAdd(a6p, __uint_as_float(v6 << 16)); atomicAdd(a6p + 1, __uint_as_float(v6 & 0xffff0000u));
    atomicAdd(a7p, __uint_as_float(v7 << 16)); atomicAdd(a7p + 1, __uint_as_float(v7 & 0xffff0000u));
  }
  for (; e < we; e += 2) {
    uint32 pk = col_tc[e];
    uint32 v = xp[(size_t)(pk & PM_C) * 32 + d];
    float* ap = smem + (size_t)((pk >> PB_C) - B0) * 68 + 2 * d;
    atomicAdd(ap, __uint_as_float(v << 16));
    atomicAdd(ap + 1, __uint_as_float(v & 0xffff0000u));
  }
  __syncthreads();

  // MFMA combine: xnew = relu(mean@Wl + X@Wr + bl) + X
  int lm = l & 15, lk = l >> 4;
  int base = B0 + w * 32;
  int r0 = base + lm;      if (r0 >= N_C) r0 = N_C - 1;
  int r1 = base + 16 + lm; if (r1 >= N_C) r1 = N_C - 1;
  const unsigned short* x0 = xch_a + (size_t)r0 * 64 + lk * 8;
  const unsigned short* x1 = xch_a + (size_t)r1 * 64 + lk * 8;
  const __bf16* wl = WlT + (size_t)lm * 64 + lk * 8;
  const __bf16* wr = WrT + (size_t)lm * 64 + lk * 8;

  // per-lane inv-degree for its two A rows
  int gA0 = base + lm, gA1 = base + 16 + lm;
  int iA0a = gA0     > N_C ? N_C : gA0;
  int iA0b = gA0 + 1 > N_C ? N_C : gA0 + 1;
  int iA1a = gA1     > N_C ? N_C : gA1;
  int iA1b = gA1 + 1 > N_C ? N_C : gA1 + 1;
  int dg0 = rowptr_c[iA0b] - rowptr_c[iA0a];
  int dg1 = rowptr_c[iA1b] - rowptr_c[iA1a];
  float inv0 = (dg0 > 0) ? (1.0f / (float)dg0) : 0.f;
  float inv1 = (dg1 > 0) ? (1.0f / (float)dg1) : 0.f;
  const float* m0p = smem + (size_t)(w * 32 + lm) * 68 + lk * 8;
  const float* m1p = smem + (size_t)(w * 32 + 16 + lm) * 68 + lk * 8;

  f32x4 acc0[4] = {{0,0,0,0},{0,0,0,0},{0,0,0,0},{0,0,0,0}};
  f32x4 acc1[4] = {{0,0,0,0},{0,0,0,0},{0,0,0,0},{0,0,0,0}};

#pragma unroll
  for (int ks = 0; ks < 64; ks += 32) {
    float4 sa0 = *(const float4*)(m0p + ks);
    float4 sb0 = *(const float4*)(m0p + ks + 4);
    float4 sa1 = *(const float4*)(m1p + ks);
    float4 sb1 = *(const float4*)(m1p + ks + 4);
    bf16x8 am0, am1;
    am0[0]=(__bf16)(sa0.x*inv0); am0[1]=(__bf16)(sa0.y*inv0); am0[2]=(__bf16)(sa0.z*inv0); am0[3]=(__bf16)(sa0.w*inv0);
    am0[4]=(__bf16)(sb0.x*inv0); am0[5]=(__bf16)(sb0.y*inv0); am0[6]=(__bf16)(sb0.z*inv0); am0[7]=(__bf16)(sb0.w*inv0);
    am1[0]=(__bf16)(sa1.x*inv1); am1[1]=(__bf16)(sa1.y*inv1); am1[2]=(__bf16)(sa1.z*inv1); am1[3]=(__bf16)(sa1.w*inv1);
    am1[4]=(__bf16)(sb1.x*inv1); am1[5]=(__bf16)(sb1.y*inv1); am1[6]=(__bf16)(sb1.z*inv1); am1[7]=(__bf16)(sb1.w*inv1);
    bf16x8 ax0 = *(const bf16x8*)(x0 + ks);
    bf16x8 ax1 = *(const bf16x8*)(x1 + ks);
#pragma unroll
    for (int fn = 0; fn < 4; ++fn) {
      bf16x8 bl_v = *(const bf16x8*)(wl + (size_t)fn * 16 * 64 + ks);
      bf16x8 br_v = *(const bf16x8*)(wr + (size_t)fn * 16 * 64 + ks);
      acc0[fn] = __builtin_amdgcn_mfma_f32_16x16x32_bf16(am0, bl_v, acc0[fn], 0, 0, 0);
      acc1[fn] = __builtin_amdgcn_mfma_f32_16x16x32_bf16(am1, bl_v, acc1[fn], 0, 0, 0);
      acc0[fn] = __builtin_amdgcn_mfma_f32_16x16x32_bf16(ax0, br_v, acc0[fn], 0, 0, 0);
      acc1[fn] = __builtin_amdgcn_mfma_f32_16x16x32_bf16(ax1, br_v, acc1[fn], 0, 0, 0);
    }
  }

#pragma unroll
  for (int fn = 0; fn < 4; ++fn) {
    int col = fn * 16 + lm;
    float bb = bl_c[col];
#pragma unroll
    for (int reg = 0; reg < 4; ++reg) {
      int row = base + lk * 4 + reg;
      if (row < N_C) {
        float xv = xc_a[(size_t)row * 64 + col];
        float o = fmaxf(acc0[fn][reg] + bb, 0.f) + xv;
        xc_n[(size_t)row * 64 + col] = o;
        xch_n[(size_t)row * 64 + col] = f2bf(o);
      }
      row = base + 16 + lk * 4 + reg;
      if (row < N_C) {
        float xv = xc_a[(size_t)row * 64 + col];
        float o = fmaxf(acc1[fn][reg] + bb, 0.f) + xv;
        xc_n[(size_t)row * 64 + col] = o;
        xch_n[(size_t)row * 64 + col] = f2bf(o);
      }
    }
  }
}

// ---------------- head: out[r] = relu(xc[r] @ Wo1 + bo1) @ Wo2 + bo2
__global__ __launch_bounds__(256) void head_kernel(
    const float* __restrict__ xc, const float* __restrict__ Wo1,
    const float* __restrict__ bo1, const float* __restrict__ Wo2,
    const float* __restrict__ bo2, float* __restrict__ out, int n)
{
  int lane = threadIdx.x & 63;
  int wid = blockIdx.x * (blockDim.x >> 6) + (threadIdx.x >> 6);
  if (wid >= n) return;
  float xv = xc[(size_t)wid * 64 + lane];
  float h = (lane < H2) ? bo1[lane] : 0.f;
  const float* wcol = Wo1 + ((lane < H2) ? lane : 0);
#pragma unroll 8
  for (int k = 0; k < 64; ++k) {
    float xk = __uint_as_float(__builtin_amdgcn_readlane(__float_as_uint(xv), k));
    h = fmaf(xk, wcol[k * H2], h);
  }
  float v = (lane < H2) ? fmaxf(h, 0.f) * Wo2[lane] : 0.f;
#pragma unroll
  for (int off = 32; off > 0; off >>= 1) v += __shfl_down(v, off, 64);
  if (lane == 0) out[wid] = v + bo2[0];
}

extern "C" void kernel_launch(void* const* d_in, const int* in_sizes, int n_in,
                              void* d_out, int out_size, void* d_ws, size_t ws_size,
                              hipStream_t stream)
{
  const float* x_comp = (const float*)d_in[0];
  const float* x_tgt  = (const float*)d_in[1];
  const int*   src_ct = (const int*)d_in[2];
  const int*   dst_ct = (const int*)d_in[3];
  const int*   src_tc = (const int*)d_in[4];
  const int*   dst_tc = (const int*)d_in[5];
  const float* Wc    = (const float*)d_in[6];
  const float* bc    = (const float*)d_in[7];
  const float* Wt    = (const float*)d_in[8];
  const float* bt    = (const float*)d_in[9];
  const float* Wl_ct = (const float*)d_in[10];
  const float* bl_ct = (const float*)d_in[11];
  const float* Wr_ct = (const float*)d_in[12];
  const float* Wl_tc = (const float*)d_in[13];
  const float* bl_tc = (const float*)d_in[14];
  const float* Wr_tc = (const float*)d_in[15];
  const float* Wo1   = (const float*)d_in[16];
  const float* bo1   = (const float*)d_in[17];
  const float* Wo2   = (const float*)d_in[18];
  const float* bo2   = (const float*)d_in[19];
  float* out = (float*)d_out;

  char* p = (char*)d_ws;
  auto alloc = [&](size_t bytes) {
    char* q = p;
    p += (bytes + 255) & ~(size_t)255;
    return q;
  };
  float* xc   = (float*)alloc((size_t)N_C * H * 4);
  float* xt   = (float*)alloc((size_t)N_T * H * 4);
  float* xc_b = (float*)alloc((size_t)N_C * H * 4);
  float* xt_b = (float*)alloc((size_t)N_T * H * 4);
  unsigned short* xch   = (unsigned short*)alloc((size_t)N_C * H * 2);
  unsigned short* xth   = (unsigned short*)alloc((size_t)N_T * H * 2);
  unsigned short* xch_b = (unsigned short*)alloc((size_t)N_C * H * 2);
  unsigned short* xth_b = (unsigned short*)alloc((size_t)N_T * H * 2);
  __bf16* WcT = (__bf16*)alloc((size_t)D_C * H * 2);
  __bf16* WtT = (__bf16*)alloc((size_t)D_T * H * 2);
  __bf16* WsT = (__bf16*)alloc((size_t)6 * H * H * 2);
  int*    h1        = (int*)alloc((size_t)NB_TOT * CCH * 4);
  int*    b1        = (int*)alloc((size_t)NB_TOT * CCH * 4);
  int*    T         = (int*)alloc((size_t)NB_TOT * 4);
  uint32* packT_t   = (uint32*)alloc((size_t)E_EDGES * 4);
  uint32* packT_c   = (uint32*)alloc((size_t)E_EDGES * 4);
  int*    rowptr_t  = (int*)alloc((size_t)(N_T + 1) * 4);
  int*    rowptr_c  = (int*)alloc((size_t)(N_C + 1) * 4);
  uint32* col_ct    = (uint32*)alloc((size_t)E_EDGES * 4);
  uint32* col_tc    = (uint32*)alloc((size_t)E_EDGES * 4);

  // node 1: weight prep + zero bucket totals
  const int PREP_TOTAL = NB_TOT + D_C * 64 + D_T * 64 + 6 * 4096;
  prep_kernel<<<dim3((PREP_TOTAL + 255) / 256), dim3(256), 0, stream>>>(
      Wc, Wt, Wl_tc, Wr_tc, WcT, WtT, WsT, T);

  // node 2: both dense input projections
  proj_kernel<<<dim3(NBC + NBT), dim3(256), 0, stream>>>(
      x_comp, WcT, bc, xc, xch, x_tgt, WtT, bt, xt, xth);

  // nodes 3-6: CSR build (two-level counting sort; col packed with full dst)
  csr1_kernel<<<dim3(2 * CCH), dim3(256), 0, stream>>>(dst_ct, dst_tc, h1, T);
  csr2_kernel<<<dim3(NB_TOT), dim3(256), 0, stream>>>(h1, T, b1);
  csr3_kernel<<<dim3(2 * CCH), dim3(256), 0, stream>>>(
      src_ct, dst_ct, src_tc, dst_tc, b1, packT_t, packT_c);
  csr4_kernel<<<dim3(NB_TOT), dim3(256), 0, stream>>>(
      b1, packT_t, packT_c, rowptr_t, col_ct, rowptr_c, col_tc);

  // nodes 7-9: one fused node per layer
  float* xc_a = xc; float* xt_a = xt;
  float* xc_n = xc_b; float* xt_n = xt_b;
  unsigned short* xch_a = xch; unsigned short* xth_a = xth;
  unsigned short* xch_n = xch_b; unsigned short* xth_n = xth_b;
  for (int l = 0; l < NL; ++l) {
    layer_kernel<<<dim3(N_T + NBC), dim3(256), 0, stream>>>(
        xch_a, xt_a, rowptr_t, col_ct,
        Wl_ct + (size_t)l * H * H, bl_ct + (size_t)l * H, Wr_ct + (size_t)l * H * H,
        xt_n, xth_n,
        xth_a, rowptr_c, col_tc,
        WsT + (size_t)l * H * H, WsT + (size_t)(3 + l) * H * H,
        bl_tc + (size_t)l * H, xc_a, xc_n, xch_n);
    float* t;
    t = xc_a; xc_a = xc_n; xc_n = t;
    t = xt_a; xt_a = xt_n; xt_n = t;
    unsigned short* th;
    th = xch_a; xch_a = xch_n; xch_n = th;
    th = xth_a; xth_a = xth_n; xth_n = th;
  }

  // node 10: output head
  head_kernel<<<dim3((N_C + 3) / 4), dim3(256), 0, stream>>>(xc_a, Wo1, bo1, Wo2, bo2, out, N_C);
}

// Round 4
// 733.667 us; speedup vs baseline: 4.1523x; 4.1523x over previous
//
#include <hip/hip_runtime.h>

typedef unsigned int uint32;
typedef __bf16 bf16x8 __attribute__((ext_vector_type(8)));
typedef float f32x4 __attribute__((ext_vector_type(4)));

constexpr int N_C = 100000, N_T = 5000, E_EDGES = 2000000;
constexpr int D_C = 1024, D_T = 1280, H = 64, H2 = 32, NL = 3;
constexpr int NBC = (N_C + 127) / 128;   // 782 MFMA blocks for compounds
constexpr int NBT = (N_T + 127) / 128;   // 40

// ---- CSR build (two-level counting sort, zero atomic-with-return) ----
constexpr int CCH = 200;                  // chunks per graph
constexpr int CHE = E_EDGES / CCH;        // 10000 edges per chunk (exact)
constexpr int SH_T = 4,  FB_T = 16;       // target: bucket = dst>>4, 16 fine bins
constexpr int SH_C = 8,  FB_C = 256;      // compound: bucket = dst>>8, 256 fine bins
constexpr int NB_T_B = (N_T + FB_T - 1) / FB_T;   // 313 buckets
constexpr int NB_C_B = (N_C + FB_C - 1) / FB_C;   // 391 buckets
constexpr int NB_TOT = NB_T_B + NB_C_B;           // 704
// packT entry: (dst<<SB)|src ; col output stores plain src
constexpr int PB_T = 17; constexpr uint32 PM_T = 0x1FFFFu;
constexpr int PB_C = 13; constexpr uint32 PM_C = 0x1FFFu;

__device__ inline unsigned short f2bf(float f) {
  uint32 u = __float_as_uint(f);
  u += 0x7fffu + ((u >> 16) & 1u);          // round-to-nearest-even
  return (unsigned short)(u >> 16);
}

// ---------------- prep: weight transposes + zero bucket totals (1 node)
__global__ __launch_bounds__(256) void prep_kernel(
    const float* __restrict__ Wc, const float* __restrict__ Wt,
    const float* __restrict__ Wl, const float* __restrict__ Wr,
    __bf16* __restrict__ WcT, __bf16* __restrict__ WtT, __bf16* __restrict__ WsT,
    int* __restrict__ T)
{
  int t = blockIdx.x * 256 + threadIdx.x;
  const int Z = NB_TOT;
  const int A = D_C * 64;
  const int B = D_T * 64;
  const int S = 6 * 64 * 64;
  if (t < Z) { T[t] = 0; return; }
  t -= Z;
  if (t < A) { int n = t & 63, k = t >> 6; WcT[(size_t)n * D_C + k] = (__bf16)Wc[(size_t)k * 64 + n]; return; }
  t -= A;
  if (t < B) { int n = t & 63, k = t >> 6; WtT[(size_t)n * D_T + k] = (__bf16)Wt[(size_t)k * 64 + n]; return; }
  t -= B;
  if (t < S) {
    int i = t >> 12;
    int r = t & 4095; int n = r & 63, k = r >> 6;
    const float* src = (i < 3) ? (Wl + (size_t)i * 4096) : (Wr + (size_t)(i - 3) * 4096);
    WsT[(size_t)i * 4096 + (size_t)n * 64 + k] = (__bf16)src[(size_t)k * 64 + n];
  }
}

// ---------------- MFMA projection body: y = relu(x @ W + b)
template<int K>
__device__ __forceinline__ void projM_body(
    const float* __restrict__ x, const __bf16* __restrict__ WT,
    const float* __restrict__ b, float* __restrict__ y,
    unsigned short* __restrict__ yh, int n, int bidx)
{
  int w = threadIdx.x >> 6, l = threadIdx.x & 63;
  int lm = l & 15, lk = l >> 4;
  int base = bidx * 128 + w * 32;
  int r0 = base + lm;      if (r0 >= n) r0 = n - 1;
  int r1 = base + 16 + lm; if (r1 >= n) r1 = n - 1;
  const float* xp0 = x + (size_t)r0 * K + lk * 8;
  const float* xp1 = x + (size_t)r1 * K + lk * 8;
  const __bf16* wp = WT + (size_t)lm * K + lk * 8;

  f32x4 acc0[4] = {{0,0,0,0},{0,0,0,0},{0,0,0,0},{0,0,0,0}};
  f32x4 acc1[4] = {{0,0,0,0},{0,0,0,0},{0,0,0,0},{0,0,0,0}};

  float4 p00 = *(const float4*)(xp0);
  float4 p01 = *(const float4*)(xp0 + 4);
  float4 p10 = *(const float4*)(xp1);
  float4 p11 = *(const float4*)(xp1 + 4);

  for (int k0 = 0; k0 < K; k0 += 32) {
    bf16x8 a0, a1;
    a0[0]=(__bf16)p00.x; a0[1]=(__bf16)p00.y; a0[2]=(__bf16)p00.z; a0[3]=(__bf16)p00.w;
    a0[4]=(__bf16)p01.x; a0[5]=(__bf16)p01.y; a0[6]=(__bf16)p01.z; a0[7]=(__bf16)p01.w;
    a1[0]=(__bf16)p10.x; a1[1]=(__bf16)p10.y; a1[2]=(__bf16)p10.z; a1[3]=(__bf16)p10.w;
    a1[4]=(__bf16)p11.x; a1[5]=(__bf16)p11.y; a1[6]=(__bf16)p11.z; a1[7]=(__bf16)p11.w;
    if (k0 + 32 < K) {
      p00 = *(const float4*)(xp0 + k0 + 32);
      p01 = *(const float4*)(xp0 + k0 + 36);
      p10 = *(const float4*)(xp1 + k0 + 32);
      p11 = *(const float4*)(xp1 + k0 + 36);
    }
#pragma unroll
    for (int fn = 0; fn < 4; ++fn) {
      bf16x8 bv = *(const bf16x8*)(wp + (size_t)fn * 16 * K + k0);
      acc0[fn] = __builtin_amdgcn_mfma_f32_16x16x32_bf16(a0, bv, acc0[fn], 0, 0, 0);
      acc1[fn] = __builtin_amdgcn_mfma_f32_16x16x32_bf16(a1, bv, acc1[fn], 0, 0, 0);
    }
  }

#pragma unroll
  for (int fn = 0; fn < 4; ++fn) {
    int col = fn * 16 + lm;
    float bb = b[col];
#pragma unroll
    for (int reg = 0; reg < 4; ++reg) {
      int row = base + lk * 4 + reg;
      if (row < n) {
        float o = fmaxf(acc0[fn][reg] + bb, 0.f);
        y[(size_t)row * 64 + col] = o;
        yh[(size_t)row * 64 + col] = f2bf(o);
      }
      row = base + 16 + lk * 4 + reg;
      if (row < n) {
        float o = fmaxf(acc1[fn][reg] + bb, 0.f);
        y[(size_t)row * 64 + col] = o;
        yh[(size_t)row * 64 + col] = f2bf(o);
      }
    }
  }
}

__global__ __launch_bounds__(256) void proj_kernel(
    const float* __restrict__ x_comp, const __bf16* __restrict__ WcT,
    const float* __restrict__ bc, float* __restrict__ xc, unsigned short* __restrict__ xch,
    const float* __restrict__ x_tgt, const __bf16* __restrict__ WtT,
    const float* __restrict__ bt, float* __restrict__ xt, unsigned short* __restrict__ xth)
{
  if (blockIdx.x < NBC) projM_body<D_C>(x_comp, WcT, bc, xc, xch, N_C, blockIdx.x);
  else                  projM_body<D_T>(x_tgt, WtT, bt, xt, xth, N_T, blockIdx.x - NBC);
}

// ---------------- csr1: per-chunk coarse-bucket histograms (LDS)
__global__ __launch_bounds__(256) void csr1_kernel(
    const int* __restrict__ dst_ct, const int* __restrict__ dst_tc,
    int* __restrict__ h1, int* __restrict__ T)
{
  __shared__ int hist[NB_C_B];
  int graph = (blockIdx.x >= CCH) ? 1 : 0;
  int chunk = graph ? (blockIdx.x - CCH) : blockIdx.x;
  const int* dst = graph ? dst_tc : dst_ct;
  int NB = graph ? NB_C_B : NB_T_B;
  int SH = graph ? SH_C : SH_T;
  for (int i = threadIdx.x; i < NB; i += 256) hist[i] = 0;
  __syncthreads();
  int e0 = chunk * CHE;
  for (int i = threadIdx.x; i < CHE; i += 256)
    atomicAdd(&hist[dst[e0 + i] >> SH], 1);
  __syncthreads();
  int* h1g = h1 + (graph ? (size_t)NB_T_B * CCH : 0);
  int* Tg  = T + (graph ? NB_T_B : 0);
  for (int i = threadIdx.x; i < NB; i += 256) {
    int v = hist[i];
    h1g[(size_t)i * CCH + chunk] = v;
    if (v) atomicAdd(&Tg[i], v);       // fire-and-forget
  }
}

// ---------------- csr2: per-bucket bases + chunk-prefix of h1 row
__global__ __launch_bounds__(256) void csr2_kernel(
    const int* __restrict__ h1, const int* __restrict__ T, int* __restrict__ b1)
{
  __shared__ int sh[256];
  __shared__ int loc2[512];
  int b = blockIdx.x;
  int graph = (b >= NB_T_B) ? 1 : 0;
  int nb = graph ? NB_C_B : NB_T_B;
  int base = graph ? NB_T_B : 0;
  int bl = b - base;
  int tid = threadIdx.x;
  int v0 = (2 * tid     < nb) ? T[base + 2 * tid]     : 0;
  int v1 = (2 * tid + 1 < nb) ? T[base + 2 * tid + 1] : 0;
  int t = v0 + v1;
  sh[tid] = t;
  __syncthreads();
  for (int off = 1; off < 256; off <<= 1) {
    int xv = (tid >= off) ? sh[tid - off] : 0;
    __syncthreads(); sh[tid] += xv; __syncthreads();
  }
  int excl = sh[tid] - t;
  loc2[2 * tid] = excl;
  loc2[2 * tid + 1] = excl + v0;
  __syncthreads();
  int B = loc2[bl];
  const int* row = h1 + (graph ? (size_t)NB_T_B * CCH : 0) + (size_t)bl * CCH;
  int hv = (tid < CCH) ? row[tid] : 0;
  sh[tid] = hv;
  __syncthreads();
  for (int off = 1; off < 256; off <<= 1) {
    int xv = (tid >= off) ? sh[tid - off] : 0;
    __syncthreads(); sh[tid] += xv; __syncthreads();
  }
  int e2 = sh[tid] - hv;
  if (tid < CCH) {
    int* b1g = b1 + (graph ? (size_t)NB_T_B * CCH : 0) + (size_t)bl * CCH;
    b1g[tid] = B + e2;
  }
}

// ---------------- csr3: scatter edges into bucket-major temp (packed)
__global__ __launch_bounds__(256) void csr3_kernel(
    const int* __restrict__ src_ct, const int* __restrict__ dst_ct,
    const int* __restrict__ src_tc, const int* __restrict__ dst_tc,
    const int* __restrict__ b1, uint32* __restrict__ packT_t, uint32* __restrict__ packT_c)
{
  __shared__ int cur[NB_C_B];
  int graph = (blockIdx.x >= CCH) ? 1 : 0;
  int chunk = graph ? (blockIdx.x - CCH) : blockIdx.x;
  const int* dst = graph ? dst_tc : dst_ct;
  const int* src = graph ? src_tc : src_ct;
  uint32* packT = graph ? packT_c : packT_t;
  int NB = graph ? NB_C_B : NB_T_B;
  int SH = graph ? SH_C : SH_T;
  int SB = graph ? PB_C : PB_T;
  const int* b1g = b1 + (graph ? (size_t)NB_T_B * CCH : 0);
  for (int i = threadIdx.x; i < NB; i += 256) cur[i] = b1g[(size_t)i * CCH + chunk];
  __syncthreads();
  int e0 = chunk * CHE;
  for (int i = threadIdx.x; i < CHE; i += 256) {
    int d = dst[e0 + i], s = src[e0 + i];
    int p = atomicAdd(&cur[d >> SH], 1);   // LDS atomic
    packT[p] = ((uint32)d << SB) | (uint32)s;
  }
}

// ---------------- csr4: per-bucket fine counting sort -> rowptr + col (plain src)
__global__ __launch_bounds__(256) void csr4_kernel(
    const int* __restrict__ b1, const uint32* __restrict__ packT_t,
    const uint32* __restrict__ packT_c,
    int* __restrict__ rowptr_t, int* __restrict__ col_ct,
    int* __restrict__ rowptr_c, int* __restrict__ col_tc)
{
  __shared__ int hist[FB_C];
  __shared__ int exc[256];
  int b = blockIdx.x;
  int graph = (b >= NB_T_B) ? 1 : 0;
  int bl = graph ? (b - NB_T_B) : b;
  int nb = graph ? NB_C_B : NB_T_B;
  int FB = graph ? FB_C : FB_T;
  int SB = graph ? PB_C : PB_T;
  uint32 SM = graph ? PM_C : PM_T;
  uint32 FMM = (uint32)(FB - 1);
  int N  = graph ? N_C : N_T;
  const uint32* packT = graph ? packT_c : packT_t;
  int* rowptr = graph ? rowptr_c : rowptr_t;
  int* col    = graph ? col_tc : col_ct;
  const int* b1g = b1 + (graph ? (size_t)NB_T_B * CCH : 0);
  int seg0 = b1g[(size_t)bl * CCH];
  int seg1 = (bl + 1 < nb) ? b1g[(size_t)(bl + 1) * CCH] : E_EDGES;
  int tid = threadIdx.x;
  if (tid < FB) hist[tid] = 0;
  __syncthreads();
  for (int i = seg0 + tid; i < seg1; i += 256)
    atomicAdd(&hist[(packT[i] >> SB) & FMM], 1);
  __syncthreads();
  int hv = (tid < FB) ? hist[tid] : 0;
  exc[tid] = hv;
  __syncthreads();
  for (int off = 1; off < 256; off <<= 1) {
    int xv = (tid >= off) ? exc[tid - off] : 0;
    __syncthreads(); exc[tid] += xv; __syncthreads();
  }
  int excl = exc[tid] - hv;
  __syncthreads();
  if (tid < FB) {
    int gbin = bl * FB + tid;
    if (gbin <= N) rowptr[gbin] = seg0 + excl;
    hist[tid] = seg0 + excl;
  }
  __syncthreads();
  for (int i = seg0 + tid; i < seg1; i += 256) {
    uint32 pk = packT[i];
    int p = atomicAdd(&hist[(pk >> SB) & FMM], 1);
    col[p] = (int)(pk & SM);                      // plain src index
  }
}

// ---------------- one node per layer: target SAGE + compound reg-acc agg + MFMA
__global__ __launch_bounds__(256) void layer_kernel(
    const unsigned short* __restrict__ xch_a, const float* __restrict__ xt_a,
    const int* __restrict__ rowptr_t, const int* __restrict__ col_ct,
    const float* __restrict__ Wl_t, const float* __restrict__ bl_t, const float* __restrict__ Wr_t,
    float* __restrict__ xt_n, unsigned short* __restrict__ xth_n,
    const unsigned short* __restrict__ xth_a, const int* __restrict__ rowptr_c,
    const int* __restrict__ col_tc,
    const __bf16* __restrict__ WlT, const __bf16* __restrict__ WrT,
    const float* __restrict__ bl_c, const float* __restrict__ xc_a,
    float* __restrict__ xc_n, unsigned short* __restrict__ xch_n)
{
  // 18.4 KB union: compound mean tile; target part/opart alias the front
  __shared__ __align__(16) uint32 smem_u[128 * 36];
  float (*part)[64]  = (float(*)[64])smem_u;
  float (*opart)[64] = (float(*)[64])(smem_u + 256);

  int l = threadIdx.x & 63, w = threadIdx.x >> 6;
  int d = l & 31, half = l >> 5;

  if (blockIdx.x < N_T) {
    // -------- target-side SAGE: one block per row; wave quarters, lane-halves by edge parity
    int r = blockIdx.x;
    int start = rowptr_t[r], end = rowptr_t[r + 1];
    int deg = end - start;
    int quarter = (deg + 3) >> 2;
    int js = start + w * quarter;
    int je = js + quarter; if (je > end) je = end;
    const uint32* xp = (const uint32*)xch_a;
    float a0 = 0.f, a1 = 0.f;
    int j = js + half;
    for (; j + 14 < je; j += 16) {
      int c0 = col_ct[j],      c1 = col_ct[j + 2];
      int c2 = col_ct[j + 4],  c3 = col_ct[j + 6];
      int c4 = col_ct[j + 8],  c5 = col_ct[j + 10];
      int c6 = col_ct[j + 12], c7 = col_ct[j + 14];
      uint32 v0 = xp[(size_t)c0 * 32 + d];
      uint32 v1 = xp[(size_t)c1 * 32 + d];
      uint32 v2 = xp[(size_t)c2 * 32 + d];
      uint32 v3 = xp[(size_t)c3 * 32 + d];
      uint32 v4 = xp[(size_t)c4 * 32 + d];
      uint32 v5 = xp[(size_t)c5 * 32 + d];
      uint32 v6 = xp[(size_t)c6 * 32 + d];
      uint32 v7 = xp[(size_t)c7 * 32 + d];
      a0 += __uint_as_float(v0 << 16); a1 += __uint_as_float(v0 & 0xffff0000u);
      a0 += __uint_as_float(v1 << 16); a1 += __uint_as_float(v1 & 0xffff0000u);
      a0 += __uint_as_float(v2 << 16); a1 += __uint_as_float(v2 & 0xffff0000u);
      a0 += __uint_as_float(v3 << 16); a1 += __uint_as_float(v3 & 0xffff0000u);
      a0 += __uint_as_float(v4 << 16); a1 += __uint_as_float(v4 & 0xffff0000u);
      a0 += __uint_as_float(v5 << 16); a1 += __uint_as_float(v5 & 0xffff0000u);
      a0 += __uint_as_float(v6 << 16); a1 += __uint_as_float(v6 & 0xffff0000u);
      a0 += __uint_as_float(v7 << 16); a1 += __uint_as_float(v7 & 0xffff0000u);
    }
    for (; j < je; j += 2) {
      uint32 v = xp[(size_t)col_ct[j] * 32 + d];
      a0 += __uint_as_float(v << 16); a1 += __uint_as_float(v & 0xffff0000u);
    }
    a0 += __shfl_xor(a0, 32, 64);
    a1 += __shfl_xor(a1, 32, 64);
    if (half == 0) *(float2*)&part[w][2 * d] = make_float2(a0, a1);
    __syncthreads();
    float m = (part[0][l] + part[1][l] + part[2][l] + part[3][l])
              * ((deg > 0) ? (1.0f / (float)deg) : 0.f);
    float xv = xt_a[(size_t)r * 64 + l];
    float o = 0.f;
    int k0 = w * 16;
#pragma unroll
    for (int kk = 0; kk < 16; ++kk) {
      int k = k0 + kk;
      float mk = __uint_as_float(__builtin_amdgcn_readlane(__float_as_uint(m), k));
      float xk = __uint_as_float(__builtin_amdgcn_readlane(__float_as_uint(xv), k));
      o = fmaf(mk, Wl_t[k * 64 + l], o);
      o = fmaf(xk, Wr_t[k * 64 + l], o);
    }
    opart[w][l] = o;
    __syncthreads();
    if (w == 0) {
      float oo = opart[0][l] + opart[1][l] + opart[2][l] + opart[3][l] + bl_t[l];
      float res = fmaxf(oo, 0.f) + xv;
      xt_n[(size_t)r * 64 + l] = res;
      xth_n[(size_t)r * 64 + l] = f2bf(res);
    }
    return;
  }

  // -------- compound side: per-row register aggregation (8-deep), then MFMA combine
  int bblk = blockIdx.x - N_T;
  int bbase = bblk * 128;

  int rp_idx = bbase + w * 32 + ((l <= 32) ? l : 32);
  if (rp_idx > N_C) rp_idx = N_C;
  int rpl = rowptr_c[rp_idx];
  const uint32* xp = (const uint32*)xth_a;

#pragma unroll 1
  for (int t = 0; t < 16; ++t) {
    int s = __shfl(rpl, 2 * t + half, 64);
    int e = __shfl(rpl, 2 * t + half + 1, 64);
    float a0 = 0.f, a1 = 0.f;
    int j = s;
    for (; j + 8 <= e; j += 8) {
      int c0 = col_tc[j],     c1 = col_tc[j + 1], c2 = col_tc[j + 2], c3 = col_tc[j + 3];
      int c4 = col_tc[j + 4], c5 = col_tc[j + 5], c6 = col_tc[j + 6], c7 = col_tc[j + 7];
      uint32 v0 = xp[(size_t)c0 * 32 + d];
      uint32 v1 = xp[(size_t)c1 * 32 + d];
      uint32 v2 = xp[(size_t)c2 * 32 + d];
      uint32 v3 = xp[(size_t)c3 * 32 + d];
      uint32 v4 = xp[(size_t)c4 * 32 + d];
      uint32 v5 = xp[(size_t)c5 * 32 + d];
      uint32 v6 = xp[(size_t)c6 * 32 + d];
      uint32 v7 = xp[(size_t)c7 * 32 + d];
      a0 += __uint_as_float(v0 << 16); a1 += __uint_as_float(v0 & 0xffff0000u);
      a0 += __uint_as_float(v1 << 16); a1 += __uint_as_float(v1 & 0xffff0000u);
      a0 += __uint_as_float(v2 << 16); a1 += __uint_as_float(v2 & 0xffff0000u);
      a0 += __uint_as_float(v3 << 16); a1 += __uint_as_float(v3 & 0xffff0000u);
      a0 += __uint_as_float(v4 << 16); a1 += __uint_as_float(v4 & 0xffff0000u);
      a0 += __uint_as_float(v5 << 16); a1 += __uint_as_float(v5 & 0xffff0000u);
      a0 += __uint_as_float(v6 << 16); a1 += __uint_as_float(v6 & 0xffff0000u);
      a0 += __uint_as_float(v7 << 16); a1 += __uint_as_float(v7 & 0xffff0000u);
    }
    for (; j < e; ++j) {
      uint32 v = xp[(size_t)col_tc[j] * 32 + d];
      a0 += __uint_as_float(v << 16); a1 += __uint_as_float(v & 0xffff0000u);
    }
    int deg = e - s;
    float inv = (deg > 0) ? (1.0f / (float)deg) : 0.f;
    uint32 packed = (uint32)f2bf(a0 * inv) | ((uint32)f2bf(a1 * inv) << 16);
    smem_u[(size_t)(w * 32 + 2 * t + half) * 36 + d] = packed;
  }
  __syncthreads();

  // MFMA combine: xnew = relu(mean@Wl + X@Wr + bl) + X
  int lm = l & 15, lk = l >> 4;
  int base = bbase + w * 32;
  int r0 = base + lm;      if (r0 >= N_C) r0 = N_C - 1;
  int r1 = base + 16 + lm; if (r1 >= N_C) r1 = N_C - 1;
  const unsigned short* x0 = xch_a + (size_t)r0 * 64 + lk * 8;
  const unsigned short* x1 = xch_a + (size_t)r1 * 64 + lk * 8;
  const __bf16* wl = WlT + (size_t)lm * 64 + lk * 8;
  const __bf16* wr = WrT + (size_t)lm * 64 + lk * 8;

  f32x4 acc0[4] = {{0,0,0,0},{0,0,0,0},{0,0,0,0},{0,0,0,0}};
  f32x4 acc1[4] = {{0,0,0,0},{0,0,0,0},{0,0,0,0},{0,0,0,0}};

#pragma unroll
  for (int ks = 0; ks < 64; ks += 32) {
    bf16x8 am0 = *(const bf16x8*)&smem_u[(size_t)(w * 32 + lm) * 36 + lk * 4 + (ks >> 1)];
    bf16x8 am1 = *(const bf16x8*)&smem_u[(size_t)(w * 32 + 16 + lm) * 36 + lk * 4 + (ks >> 1)];
    bf16x8 ax0 = *(const bf16x8*)(x0 + ks);
    bf16x8 ax1 = *(const bf16x8*)(x1 + ks);
#pragma unroll
    for (int fn = 0; fn < 4; ++fn) {
      bf16x8 bl_v = *(const bf16x8*)(wl + (size_t)fn * 16 * 64 + ks);
      bf16x8 br_v = *(const bf16x8*)(wr + (size_t)fn * 16 * 64 + ks);
      acc0[fn] = __builtin_amdgcn_mfma_f32_16x16x32_bf16(am0, bl_v, acc0[fn], 0, 0, 0);
      acc1[fn] = __builtin_amdgcn_mfma_f32_16x16x32_bf16(am1, bl_v, acc1[fn], 0, 0, 0);
      acc0[fn] = __builtin_amdgcn_mfma_f32_16x16x32_bf16(ax0, br_v, acc0[fn], 0, 0, 0);
      acc1[fn] = __builtin_amdgcn_mfma_f32_16x16x32_bf16(ax1, br_v, acc1[fn], 0, 0, 0);
    }
  }

#pragma unroll
  for (int fn = 0; fn < 4; ++fn) {
    int col = fn * 16 + lm;
    float bb = bl_c[col];
#pragma unroll
    for (int reg = 0; reg < 4; ++reg) {
      int row = base + lk * 4 + reg;
      if (row < N_C) {
        float xv = xc_a[(size_t)row * 64 + col];
        float o = fmaxf(acc0[fn][reg] + bb, 0.f) + xv;
        xc_n[(size_t)row * 64 + col] = o;
        xch_n[(size_t)row * 64 + col] = f2bf(o);
      }
      row = base + 16 + lk * 4 + reg;
      if (row < N_C) {
        float xv = xc_a[(size_t)row * 64 + col];
        float o = fmaxf(acc1[fn][reg] + bb, 0.f) + xv;
        xc_n[(size_t)row * 64 + col] = o;
        xch_n[(size_t)row * 64 + col] = f2bf(o);
      }
    }
  }
}

// ---------------- head: out[r] = relu(xc[r] @ Wo1 + bo1) @ Wo2 + bo2
__global__ __launch_bounds__(256) void head_kernel(
    const float* __restrict__ xc, const float* __restrict__ Wo1,
    const float* __restrict__ bo1, const float* __restrict__ Wo2,
    const float* __restrict__ bo2, float* __restrict__ out, int n)
{
  int lane = threadIdx.x & 63;
  int wid = blockIdx.x * (blockDim.x >> 6) + (threadIdx.x >> 6);
  if (wid >= n) return;
  float xv = xc[(size_t)wid * 64 + lane];
  float h = (lane < H2) ? bo1[lane] : 0.f;
  const float* wcol = Wo1 + ((lane < H2) ? lane : 0);
#pragma unroll 8
  for (int k = 0; k < 64; ++k) {
    float xk = __uint_as_float(__builtin_amdgcn_readlane(__float_as_uint(xv), k));
    h = fmaf(xk, wcol[k * H2], h);
  }
  float v = (lane < H2) ? fmaxf(h, 0.f) * Wo2[lane] : 0.f;
#pragma unroll
  for (int off = 32; off > 0; off >>= 1) v += __shfl_down(v, off, 64);
  if (lane == 0) out[wid] = v + bo2[0];
}

extern "C" void kernel_launch(void* const* d_in, const int* in_sizes, int n_in,
                              void* d_out, int out_size, void* d_ws, size_t ws_size,
                              hipStream_t stream)
{
  const float* x_comp = (const float*)d_in[0];
  const float* x_tgt  = (const float*)d_in[1];
  const int*   src_ct = (const int*)d_in[2];
  const int*   dst_ct = (const int*)d_in[3];
  const int*   src_tc = (const int*)d_in[4];
  const int*   dst_tc = (const int*)d_in[5];
  const float* Wc    = (const float*)d_in[6];
  const float* bc    = (const float*)d_in[7];
  const float* Wt    = (const float*)d_in[8];
  const float* bt    = (const float*)d_in[9];
  const float* Wl_ct = (const float*)d_in[10];
  const float* bl_ct = (const float*)d_in[11];
  const float* Wr_ct = (const float*)d_in[12];
  const float* Wl_tc = (const float*)d_in[13];
  const float* bl_tc = (const float*)d_in[14];
  const float* Wr_tc = (const float*)d_in[15];
  const float* Wo1   = (const float*)d_in[16];
  const float* bo1   = (const float*)d_in[17];
  const float* Wo2   = (const float*)d_in[18];
  const float* bo2   = (const float*)d_in[19];
  float* out = (float*)d_out;

  char* p = (char*)d_ws;
  auto alloc = [&](size_t bytes) {
    char* q = p;
    p += (bytes + 255) & ~(size_t)255;
    return q;
  };
  float* xc   = (float*)alloc((size_t)N_C * H * 4);
  float* xt   = (float*)alloc((size_t)N_T * H * 4);
  float* xc_b = (float*)alloc((size_t)N_C * H * 4);
  float* xt_b = (float*)alloc((size_t)N_T * H * 4);
  unsigned short* xch   = (unsigned short*)alloc((size_t)N_C * H * 2);
  unsigned short* xth   = (unsigned short*)alloc((size_t)N_T * H * 2);
  unsigned short* xch_b = (unsigned short*)alloc((size_t)N_C * H * 2);
  unsigned short* xth_b = (unsigned short*)alloc((size_t)N_T * H * 2);
  __bf16* WcT = (__bf16*)alloc((size_t)D_C * H * 2);
  __bf16* WtT = (__bf16*)alloc((size_t)D_T * H * 2);
  __bf16* WsT = (__bf16*)alloc((size_t)6 * H * H * 2);
  int*    h1        = (int*)alloc((size_t)NB_TOT * CCH * 4);
  int*    b1        = (int*)alloc((size_t)NB_TOT * CCH * 4);
  int*    T         = (int*)alloc((size_t)NB_TOT * 4);
  uint32* packT_t   = (uint32*)alloc((size_t)E_EDGES * 4);
  uint32* packT_c   = (uint32*)alloc((size_t)E_EDGES * 4);
  int*    rowptr_t  = (int*)alloc((size_t)(N_T + 1) * 4);
  int*    rowptr_c  = (int*)alloc((size_t)(N_C + 1) * 4);
  int*    col_ct    = (int*)alloc((size_t)E_EDGES * 4);
  int*    col_tc    = (int*)alloc((size_t)E_EDGES * 4);

  // node 1: weight prep + zero bucket totals
  const int PREP_TOTAL = NB_TOT + D_C * 64 + D_T * 64 + 6 * 4096;
  prep_kernel<<<dim3((PREP_TOTAL + 255) / 256), dim3(256), 0, stream>>>(
      Wc, Wt, Wl_tc, Wr_tc, WcT, WtT, WsT, T);

  // node 2: both dense input projections
  proj_kernel<<<dim3(NBC + NBT), dim3(256), 0, stream>>>(
      x_comp, WcT, bc, xc, xch, x_tgt, WtT, bt, xt, xth);

  // nodes 3-6: CSR build (two-level counting sort)
  csr1_kernel<<<dim3(2 * CCH), dim3(256), 0, stream>>>(dst_ct, dst_tc, h1, T);
  csr2_kernel<<<dim3(NB_TOT), dim3(256), 0, stream>>>(h1, T, b1);
  csr3_kernel<<<dim3(2 * CCH), dim3(256), 0, stream>>>(
      src_ct, dst_ct, src_tc, dst_tc, b1, packT_t, packT_c);
  csr4_kernel<<<dim3(NB_TOT), dim3(256), 0, stream>>>(
      b1, packT_t, packT_c, rowptr_t, col_ct, rowptr_c, col_tc);

  // nodes 7-9: one fused node per layer
  float* xc_a = xc; float* xt_a = xt;
  float* xc_n = xc_b; float* xt_n = xt_b;
  unsigned short* xch_a = xch; unsigned short* xth_a = xth;
  unsigned short* xch_n = xch_b; unsigned short* xth_n = xth_b;
  for (int l = 0; l < NL; ++l) {
    layer_kernel<<<dim3(N_T + NBC), dim3(256), 0, stream>>>(
        xch_a, xt_a, rowptr_t, col_ct,
        Wl_ct + (size_t)l * H * H, bl_ct + (size_t)l * H, Wr_ct + (size_t)l * H * H,
        xt_n, xth_n,
        xth_a, rowptr_c, col_tc,
        WsT + (size_t)l * H * H, WsT + (size_t)(3 + l) * H * H,
        bl_tc + (size_t)l * H, xc_a, xc_n, xch_n);
    float* t;
    t = xc_a; xc_a = xc_n; xc_n = t;
    t = xt_a; xt_a = xt_n; xt_n = t;
    unsigned short* th;
    th = xch_a; xch_a = xch_n; xch_n = th;
    th = xth_a; xth_a = xth_n; xth_n = th;
  }

  // node 10: output head
  head_kernel<<<dim3((N_C + 3) / 4), dim3(256), 0, stream>>>(xc_a, Wo1, bo1, Wo2, bo2, out, N_C);
}

// Round 5
// 676.710 us; speedup vs baseline: 4.5017x; 1.0842x over previous
//
#include <hip/hip_runtime.h>

typedef unsigned int uint32;
typedef __bf16 bf16x8 __attribute__((ext_vector_type(8)));
typedef float f32x4 __attribute__((ext_vector_type(4)));

constexpr int N_C = 100000, N_T = 5000, E_EDGES = 2000000;
constexpr int D_C = 1024, D_T = 1280, H = 64, H2 = 32, NL = 3;
constexpr int NBC = (N_C + 127) / 128;   // 782 MFMA blocks for compounds
constexpr int NBT = (N_T + 127) / 128;   // 40

// ---- CSR build (two-level counting sort, zero atomic-with-return) ----
constexpr int CCH = 200;                  // chunks per graph
constexpr int CHE = E_EDGES / CCH;        // 10000 edges per chunk (exact)
constexpr int SH_T = 4,  FB_T = 16;       // target: bucket = dst>>4, 16 fine bins
constexpr int SH_C = 8,  FB_C = 256;      // compound: bucket = dst>>8, 256 fine bins
constexpr int NB_T_B = (N_T + FB_T - 1) / FB_T;   // 313 buckets
constexpr int NB_C_B = (N_C + FB_C - 1) / FB_C;   // 391 buckets
constexpr int NB_TOT = NB_T_B + NB_C_B;           // 704
// packT entry: (dst<<SB)|src ; col output stores plain src
constexpr int PB_T = 17; constexpr uint32 PM_T = 0x1FFFFu;
constexpr int PB_C = 13; constexpr uint32 PM_C = 0x1FFFu;

__device__ inline unsigned short f2bf(float f) {
  uint32 u = __float_as_uint(f);
  u += 0x7fffu + ((u >> 16) & 1u);          // round-to-nearest-even
  return (unsigned short)(u >> 16);
}

// ---------------- prep: weight transposes + zero bucket totals (1 node)
__global__ __launch_bounds__(256) void prep_kernel(
    const float* __restrict__ Wc, const float* __restrict__ Wt,
    const float* __restrict__ Wl, const float* __restrict__ Wr,
    __bf16* __restrict__ WcT, __bf16* __restrict__ WtT, __bf16* __restrict__ WsT,
    int* __restrict__ T)
{
  int t = blockIdx.x * 256 + threadIdx.x;
  const int Z = NB_TOT;
  const int A = D_C * 64;
  const int B = D_T * 64;
  const int S = 6 * 64 * 64;
  if (t < Z) { T[t] = 0; return; }
  t -= Z;
  if (t < A) { int n = t & 63, k = t >> 6; WcT[(size_t)n * D_C + k] = (__bf16)Wc[(size_t)k * 64 + n]; return; }
  t -= A;
  if (t < B) { int n = t & 63, k = t >> 6; WtT[(size_t)n * D_T + k] = (__bf16)Wt[(size_t)k * 64 + n]; return; }
  t -= B;
  if (t < S) {
    int i = t >> 12;
    int r = t & 4095; int n = r & 63, k = r >> 6;
    const float* src = (i < 3) ? (Wl + (size_t)i * 4096) : (Wr + (size_t)(i - 3) * 4096);
    WsT[(size_t)i * 4096 + (size_t)n * 64 + k] = (__bf16)src[(size_t)k * 64 + n];
  }
}

// ---------------- MFMA projection body: y = relu(x @ W + b)
template<int K>
__device__ __forceinline__ void projM_body(
    const float* __restrict__ x, const __bf16* __restrict__ WT,
    const float* __restrict__ b, float* __restrict__ y,
    unsigned short* __restrict__ yh, int n, int bidx)
{
  int w = threadIdx.x >> 6, l = threadIdx.x & 63;
  int lm = l & 15, lk = l >> 4;
  int base = bidx * 128 + w * 32;
  int r0 = base + lm;      if (r0 >= n) r0 = n - 1;
  int r1 = base + 16 + lm; if (r1 >= n) r1 = n - 1;
  const float* xp0 = x + (size_t)r0 * K + lk * 8;
  const float* xp1 = x + (size_t)r1 * K + lk * 8;
  const __bf16* wp = WT + (size_t)lm * K + lk * 8;

  f32x4 acc0[4] = {{0,0,0,0},{0,0,0,0},{0,0,0,0},{0,0,0,0}};
  f32x4 acc1[4] = {{0,0,0,0},{0,0,0,0},{0,0,0,0},{0,0,0,0}};

  float4 p00 = *(const float4*)(xp0);
  float4 p01 = *(const float4*)(xp0 + 4);
  float4 p10 = *(const float4*)(xp1);
  float4 p11 = *(const float4*)(xp1 + 4);

  for (int k0 = 0; k0 < K; k0 += 32) {
    bf16x8 a0, a1;
    a0[0]=(__bf16)p00.x; a0[1]=(__bf16)p00.y; a0[2]=(__bf16)p00.z; a0[3]=(__bf16)p00.w;
    a0[4]=(__bf16)p01.x; a0[5]=(__bf16)p01.y; a0[6]=(__bf16)p01.z; a0[7]=(__bf16)p01.w;
    a1[0]=(__bf16)p10.x; a1[1]=(__bf16)p10.y; a1[2]=(__bf16)p10.z; a1[3]=(__bf16)p10.w;
    a1[4]=(__bf16)p11.x; a1[5]=(__bf16)p11.y; a1[6]=(__bf16)p11.z; a1[7]=(__bf16)p11.w;
    if (k0 + 32 < K) {
      p00 = *(const float4*)(xp0 + k0 + 32);
      p01 = *(const float4*)(xp0 + k0 + 36);
      p10 = *(const float4*)(xp1 + k0 + 32);
      p11 = *(const float4*)(xp1 + k0 + 36);
    }
#pragma unroll
    for (int fn = 0; fn < 4; ++fn) {
      bf16x8 bv = *(const bf16x8*)(wp + (size_t)fn * 16 * K + k0);
      acc0[fn] = __builtin_amdgcn_mfma_f32_16x16x32_bf16(a0, bv, acc0[fn], 0, 0, 0);
      acc1[fn] = __builtin_amdgcn_mfma_f32_16x16x32_bf16(a1, bv, acc1[fn], 0, 0, 0);
    }
  }

#pragma unroll
  for (int fn = 0; fn < 4; ++fn) {
    int col = fn * 16 + lm;
    float bb = b[col];
#pragma unroll
    for (int reg = 0; reg < 4; ++reg) {
      int row = base + lk * 4 + reg;
      if (row < n) {
        float o = fmaxf(acc0[fn][reg] + bb, 0.f);
        y[(size_t)row * 64 + col] = o;
        yh[(size_t)row * 64 + col] = f2bf(o);
      }
      row = base + 16 + lk * 4 + reg;
      if (row < n) {
        float o = fmaxf(acc1[fn][reg] + bb, 0.f);
        y[(size_t)row * 64 + col] = o;
        yh[(size_t)row * 64 + col] = f2bf(o);
      }
    }
  }
}

__global__ __launch_bounds__(256) void proj_kernel(
    const float* __restrict__ x_comp, const __bf16* __restrict__ WcT,
    const float* __restrict__ bc, float* __restrict__ xc, unsigned short* __restrict__ xch,
    const float* __restrict__ x_tgt, const __bf16* __restrict__ WtT,
    const float* __restrict__ bt, float* __restrict__ xt, unsigned short* __restrict__ xth)
{
  if (blockIdx.x < NBC) projM_body<D_C>(x_comp, WcT, bc, xc, xch, N_C, blockIdx.x);
  else                  projM_body<D_T>(x_tgt, WtT, bt, xt, xth, N_T, blockIdx.x - NBC);
}

// ---------------- csr1: per-chunk coarse-bucket histograms (LDS)
__global__ __launch_bounds__(256) void csr1_kernel(
    const int* __restrict__ dst_ct, const int* __restrict__ dst_tc,
    int* __restrict__ h1, int* __restrict__ T)
{
  __shared__ int hist[NB_C_B];
  int graph = (blockIdx.x >= CCH) ? 1 : 0;
  int chunk = graph ? (blockIdx.x - CCH) : blockIdx.x;
  const int* dst = graph ? dst_tc : dst_ct;
  int NB = graph ? NB_C_B : NB_T_B;
  int SH = graph ? SH_C : SH_T;
  for (int i = threadIdx.x; i < NB; i += 256) hist[i] = 0;
  __syncthreads();
  int e0 = chunk * CHE;
  for (int i = threadIdx.x; i < CHE; i += 256)
    atomicAdd(&hist[dst[e0 + i] >> SH], 1);
  __syncthreads();
  int* h1g = h1 + (graph ? (size_t)NB_T_B * CCH : 0);
  int* Tg  = T + (graph ? NB_T_B : 0);
  for (int i = threadIdx.x; i < NB; i += 256) {
    int v = hist[i];
    h1g[(size_t)i * CCH + chunk] = v;
    if (v) atomicAdd(&Tg[i], v);       // fire-and-forget
  }
}

// ---------------- csr2: per-bucket bases + chunk-prefix of h1 row
__global__ __launch_bounds__(256) void csr2_kernel(
    const int* __restrict__ h1, const int* __restrict__ T, int* __restrict__ b1)
{
  __shared__ int sh[256];
  __shared__ int loc2[512];
  int b = blockIdx.x;
  int graph = (b >= NB_T_B) ? 1 : 0;
  int nb = graph ? NB_C_B : NB_T_B;
  int base = graph ? NB_T_B : 0;
  int bl = b - base;
  int tid = threadIdx.x;
  int v0 = (2 * tid     < nb) ? T[base + 2 * tid]     : 0;
  int v1 = (2 * tid + 1 < nb) ? T[base + 2 * tid + 1] : 0;
  int t = v0 + v1;
  sh[tid] = t;
  __syncthreads();
  for (int off = 1; off < 256; off <<= 1) {
    int xv = (tid >= off) ? sh[tid - off] : 0;
    __syncthreads(); sh[tid] += xv; __syncthreads();
  }
  int excl = sh[tid] - t;
  loc2[2 * tid] = excl;
  loc2[2 * tid + 1] = excl + v0;
  __syncthreads();
  int B = loc2[bl];
  const int* row = h1 + (graph ? (size_t)NB_T_B * CCH : 0) + (size_t)bl * CCH;
  int hv = (tid < CCH) ? row[tid] : 0;
  sh[tid] = hv;
  __syncthreads();
  for (int off = 1; off < 256; off <<= 1) {
    int xv = (tid >= off) ? sh[tid - off] : 0;
    __syncthreads(); sh[tid] += xv; __syncthreads();
  }
  int e2 = sh[tid] - hv;
  if (tid < CCH) {
    int* b1g = b1 + (graph ? (size_t)NB_T_B * CCH : 0) + (size_t)bl * CCH;
    b1g[tid] = B + e2;
  }
}

// ---------------- csr3: scatter edges into bucket-major temp (packed)
__global__ __launch_bounds__(256) void csr3_kernel(
    const int* __restrict__ src_ct, const int* __restrict__ dst_ct,
    const int* __restrict__ src_tc, const int* __restrict__ dst_tc,
    const int* __restrict__ b1, uint32* __restrict__ packT_t, uint32* __restrict__ packT_c)
{
  __shared__ int cur[NB_C_B];
  int graph = (blockIdx.x >= CCH) ? 1 : 0;
  int chunk = graph ? (blockIdx.x - CCH) : blockIdx.x;
  const int* dst = graph ? dst_tc : dst_ct;
  const int* src = graph ? src_tc : src_ct;
  uint32* packT = graph ? packT_c : packT_t;
  int NB = graph ? NB_C_B : NB_T_B;
  int SH = graph ? SH_C : SH_T;
  int SB = graph ? PB_C : PB_T;
  const int* b1g = b1 + (graph ? (size_t)NB_T_B * CCH : 0);
  for (int i = threadIdx.x; i < NB; i += 256) cur[i] = b1g[(size_t)i * CCH + chunk];
  __syncthreads();
  int e0 = chunk * CHE;
  for (int i = threadIdx.x; i < CHE; i += 256) {
    int d = dst[e0 + i], s = src[e0 + i];
    int p = atomicAdd(&cur[d >> SH], 1);   // LDS atomic
    packT[p] = ((uint32)d << SB) | (uint32)s;
  }
}

// ---------------- csr4: per-bucket fine counting sort -> rowptr + col (plain src)
__global__ __launch_bounds__(256) void csr4_kernel(
    const int* __restrict__ b1, const uint32* __restrict__ packT_t,
    const uint32* __restrict__ packT_c,
    int* __restrict__ rowptr_t, int* __restrict__ col_ct,
    int* __restrict__ rowptr_c, int* __restrict__ col_tc)
{
  __shared__ int hist[FB_C];
  __shared__ int exc[256];
  int b = blockIdx.x;
  int graph = (b >= NB_T_B) ? 1 : 0;
  int bl = graph ? (b - NB_T_B) : b;
  int nb = graph ? NB_C_B : NB_T_B;
  int FB = graph ? FB_C : FB_T;
  int SB = graph ? PB_C : PB_T;
  uint32 SM = graph ? PM_C : PM_T;
  uint32 FMM = (uint32)(FB - 1);
  int N  = graph ? N_C : N_T;
  const uint32* packT = graph ? packT_c : packT_t;
  int* rowptr = graph ? rowptr_c : rowptr_t;
  int* col    = graph ? col_tc : col_ct;
  const int* b1g = b1 + (graph ? (size_t)NB_T_B * CCH : 0);
  int seg0 = b1g[(size_t)bl * CCH];
  int seg1 = (bl + 1 < nb) ? b1g[(size_t)(bl + 1) * CCH] : E_EDGES;
  int tid = threadIdx.x;
  if (tid < FB) hist[tid] = 0;
  __syncthreads();
  for (int i = seg0 + tid; i < seg1; i += 256)
    atomicAdd(&hist[(packT[i] >> SB) & FMM], 1);
  __syncthreads();
  int hv = (tid < FB) ? hist[tid] : 0;
  exc[tid] = hv;
  __syncthreads();
  for (int off = 1; off < 256; off <<= 1) {
    int xv = (tid >= off) ? exc[tid - off] : 0;
    __syncthreads(); exc[tid] += xv; __syncthreads();
  }
  int excl = exc[tid] - hv;
  __syncthreads();
  if (tid < FB) {
    int gbin = bl * FB + tid;
    if (gbin <= N) rowptr[gbin] = seg0 + excl;
    hist[tid] = seg0 + excl;
  }
  __syncthreads();
  for (int i = seg0 + tid; i < seg1; i += 256) {
    uint32 pk = packT[i];
    int p = atomicAdd(&hist[(pk >> SB) & FMM], 1);
    col[p] = (int)(pk & SM);                      // plain src index
  }
}

// ---------------- layerT: target-side SAGE, one block per row (masked batch gather)
__global__ __launch_bounds__(256) void layerT_kernel(
    const unsigned short* __restrict__ xch_a, const float* __restrict__ xt_a,
    const int* __restrict__ rowptr_t, const int* __restrict__ col_ct,
    const float* __restrict__ Wl_t, const float* __restrict__ bl_t, const float* __restrict__ Wr_t,
    float* __restrict__ xt_n, unsigned short* __restrict__ xth_n)
{
  __shared__ __align__(16) float part[4][64];
  __shared__ __align__(16) float opart[4][64];

  int l = threadIdx.x & 63, w = threadIdx.x >> 6;
  int d = l & 31, half = l >> 5;

  int r = blockIdx.x;
  int start = rowptr_t[r], end = rowptr_t[r + 1];
  int deg = end - start;
  int quarter = (deg + 3) >> 2;
  int js = start + w * quarter;
  int je = js + quarter; if (je > end) je = end;
  const uint32* xp = (const uint32*)xch_a;
  float a0 = 0.f, a1 = 0.f;
  int j0 = js + half;
  for (int j = j0; j < je; j += 16) {      // 8 masked edges per half per batch
    int idx[8]; uint32 vv[8];
#pragma unroll
    for (int k = 0; k < 8; ++k) {
      int jj = j + 2 * k;
      idx[k] = col_ct[(jj < je) ? jj : j];
    }
#pragma unroll
    for (int k = 0; k < 8; ++k) vv[k] = xp[(size_t)idx[k] * 32 + d];
#pragma unroll
    for (int k = 0; k < 8; ++k) {
      bool m = (j + 2 * k) < je;
      a0 += m ? __uint_as_float(vv[k] << 16) : 0.f;
      a1 += m ? __uint_as_float(vv[k] & 0xffff0000u) : 0.f;
    }
  }
  a0 += __shfl_xor(a0, 32, 64);
  a1 += __shfl_xor(a1, 32, 64);
  if (half == 0) *(float2*)&part[w][2 * d] = make_float2(a0, a1);
  __syncthreads();
  float m = (part[0][l] + part[1][l] + part[2][l] + part[3][l])
            * ((deg > 0) ? (1.0f / (float)deg) : 0.f);
  float xv = xt_a[(size_t)r * 64 + l];
  float o = 0.f;
  int k0 = w * 16;
#pragma unroll
  for (int kk = 0; kk < 16; ++kk) {
    int k = k0 + kk;
    float mk = __uint_as_float(__builtin_amdgcn_readlane(__float_as_uint(m), k));
    float xk = __uint_as_float(__builtin_amdgcn_readlane(__float_as_uint(xv), k));
    o = fmaf(mk, Wl_t[k * 64 + l], o);
    o = fmaf(xk, Wr_t[k * 64 + l], o);
  }
  opart[w][l] = o;
  __syncthreads();
  if (w == 0) {
    float oo = opart[0][l] + opart[1][l] + opart[2][l] + opart[3][l] + bl_t[l];
    float res = fmaxf(oo, 0.f) + xv;
    xt_n[(size_t)r * 64 + l] = res;
    xth_n[(size_t)r * 64 + l] = f2bf(res);
  }
}

// ---------------- layerC: compound-side reg-acc agg (masked batch) + MFMA combine
__global__ __launch_bounds__(256) void layerC_kernel(
    const unsigned short* __restrict__ xch_a,
    const unsigned short* __restrict__ xth_a, const int* __restrict__ rowptr_c,
    const int* __restrict__ col_tc,
    const __bf16* __restrict__ WlT, const __bf16* __restrict__ WrT,
    const float* __restrict__ bl_c, const float* __restrict__ xc_a,
    float* __restrict__ xc_n, unsigned short* __restrict__ xch_n)
{
  __shared__ __align__(16) uint32 smem_u[128 * 36];   // packed bf16 means, padded rows

  int l = threadIdx.x & 63, w = threadIdx.x >> 6;
  int d = l & 31, half = l >> 5;

  int bbase = blockIdx.x * 128;

  int rp_idx = bbase + w * 32 + ((l <= 32) ? l : 32);
  if (rp_idx > N_C) rp_idx = N_C;
  int rpl = rowptr_c[rp_idx];
  const uint32* xp = (const uint32*)xth_a;

#pragma unroll 1
  for (int t = 0; t < 16; ++t) {
    int s = __shfl(rpl, 2 * t + half, 64);
    int e = __shfl(rpl, 2 * t + half + 1, 64);
    float a0 = 0.f, a1 = 0.f;
    int n = e - s;
    for (int j = 0; j < n; j += 8) {       // masked batch of 8, no serial tail
      int idx[8]; uint32 vv[8];
#pragma unroll
      for (int k = 0; k < 8; ++k) {
        int jj = s + j + k;
        idx[k] = col_tc[(jj < e) ? jj : s];
      }
#pragma unroll
      for (int k = 0; k < 8; ++k) vv[k] = xp[(size_t)idx[k] * 32 + d];
#pragma unroll
      for (int k = 0; k < 8; ++k) {
        bool m = (j + k) < n;
        a0 += m ? __uint_as_float(vv[k] << 16) : 0.f;
        a1 += m ? __uint_as_float(vv[k] & 0xffff0000u) : 0.f;
      }
    }
    float inv = (n > 0) ? (1.0f / (float)n) : 0.f;
    uint32 packed = (uint32)f2bf(a0 * inv) | ((uint32)f2bf(a1 * inv) << 16);
    smem_u[(size_t)(w * 32 + 2 * t + half) * 36 + d] = packed;
  }
  __syncthreads();

  // MFMA combine: xnew = relu(mean@Wl + X@Wr + bl) + X
  int lm = l & 15, lk = l >> 4;
  int base = bbase + w * 32;
  int r0 = base + lm;      if (r0 >= N_C) r0 = N_C - 1;
  int r1 = base + 16 + lm; if (r1 >= N_C) r1 = N_C - 1;
  const unsigned short* x0 = xch_a + (size_t)r0 * 64 + lk * 8;
  const unsigned short* x1 = xch_a + (size_t)r1 * 64 + lk * 8;
  const __bf16* wl = WlT + (size_t)lm * 64 + lk * 8;
  const __bf16* wr = WrT + (size_t)lm * 64 + lk * 8;

  f32x4 acc0[4] = {{0,0,0,0},{0,0,0,0},{0,0,0,0},{0,0,0,0}};
  f32x4 acc1[4] = {{0,0,0,0},{0,0,0,0},{0,0,0,0},{0,0,0,0}};

#pragma unroll
  for (int ks = 0; ks < 64; ks += 32) {
    bf16x8 am0 = *(const bf16x8*)&smem_u[(size_t)(w * 32 + lm) * 36 + lk * 4 + (ks >> 1)];
    bf16x8 am1 = *(const bf16x8*)&smem_u[(size_t)(w * 32 + 16 + lm) * 36 + lk * 4 + (ks >> 1)];
    bf16x8 ax0 = *(const bf16x8*)(x0 + ks);
    bf16x8 ax1 = *(const bf16x8*)(x1 + ks);
#pragma unroll
    for (int fn = 0; fn < 4; ++fn) {
      bf16x8 bl_v = *(const bf16x8*)(wl + (size_t)fn * 16 * 64 + ks);
      bf16x8 br_v = *(const bf16x8*)(wr + (size_t)fn * 16 * 64 + ks);
      acc0[fn] = __builtin_amdgcn_mfma_f32_16x16x32_bf16(am0, bl_v, acc0[fn], 0, 0, 0);
      acc1[fn] = __builtin_amdgcn_mfma_f32_16x16x32_bf16(am1, bl_v, acc1[fn], 0, 0, 0);
      acc0[fn] = __builtin_amdgcn_mfma_f32_16x16x32_bf16(ax0, br_v, acc0[fn], 0, 0, 0);
      acc1[fn] = __builtin_amdgcn_mfma_f32_16x16x32_bf16(ax1, br_v, acc1[fn], 0, 0, 0);
    }
  }

#pragma unroll
  for (int fn = 0; fn < 4; ++fn) {
    int col = fn * 16 + lm;
    float bb = bl_c[col];
#pragma unroll
    for (int reg = 0; reg < 4; ++reg) {
      int row = base + lk * 4 + reg;
      if (row < N_C) {
        float xv = xc_a[(size_t)row * 64 + col];
        float o = fmaxf(acc0[fn][reg] + bb, 0.f) + xv;
        xc_n[(size_t)row * 64 + col] = o;
        xch_n[(size_t)row * 64 + col] = f2bf(o);
      }
      row = base + 16 + lk * 4 + reg;
      if (row < N_C) {
        float xv = xc_a[(size_t)row * 64 + col];
        float o = fmaxf(acc1[fn][reg] + bb, 0.f) + xv;
        xc_n[(size_t)row * 64 + col] = o;
        xch_n[(size_t)row * 64 + col] = f2bf(o);
      }
    }
  }
}

// ---------------- head: out[r] = relu(xc[r] @ Wo1 + bo1) @ Wo2 + bo2
__global__ __launch_bounds__(256) void head_kernel(
    const float* __restrict__ xc, const float* __restrict__ Wo1,
    const float* __restrict__ bo1, const float* __restrict__ Wo2,
    const float* __restrict__ bo2, float* __restrict__ out, int n)
{
  int lane = threadIdx.x & 63;
  int wid = blockIdx.x * (blockDim.x >> 6) + (threadIdx.x >> 6);
  if (wid >= n) return;
  float xv = xc[(size_t)wid * 64 + lane];
  float h = (lane < H2) ? bo1[lane] : 0.f;
  const float* wcol = Wo1 + ((lane < H2) ? lane : 0);
#pragma unroll 8
  for (int k = 0; k < 64; ++k) {
    float xk = __uint_as_float(__builtin_amdgcn_readlane(__float_as_uint(xv), k));
    h = fmaf(xk, wcol[k * H2], h);
  }
  float v = (lane < H2) ? fmaxf(h, 0.f) * Wo2[lane] : 0.f;
#pragma unroll
  for (int off = 32; off > 0; off >>= 1) v += __shfl_down(v, off, 64);
  if (lane == 0) out[wid] = v + bo2[0];
}

extern "C" void kernel_launch(void* const* d_in, const int* in_sizes, int n_in,
                              void* d_out, int out_size, void* d_ws, size_t ws_size,
                              hipStream_t stream)
{
  const float* x_comp = (const float*)d_in[0];
  const float* x_tgt  = (const float*)d_in[1];
  const int*   src_ct = (const int*)d_in[2];
  const int*   dst_ct = (const int*)d_in[3];
  const int*   src_tc = (const int*)d_in[4];
  const int*   dst_tc = (const int*)d_in[5];
  const float* Wc    = (const float*)d_in[6];
  const float* bc    = (const float*)d_in[7];
  const float* Wt    = (const float*)d_in[8];
  const float* bt    = (const float*)d_in[9];
  const float* Wl_ct = (const float*)d_in[10];
  const float* bl_ct = (const float*)d_in[11];
  const float* Wr_ct = (const float*)d_in[12];
  const float* Wl_tc = (const float*)d_in[13];
  const float* bl_tc = (const float*)d_in[14];
  const float* Wr_tc = (const float*)d_in[15];
  const float* Wo1   = (const float*)d_in[16];
  const float* bo1   = (const float*)d_in[17];
  const float* Wo2   = (const float*)d_in[18];
  const float* bo2   = (const float*)d_in[19];
  float* out = (float*)d_out;

  char* p = (char*)d_ws;
  auto alloc = [&](size_t bytes) {
    char* q = p;
    p += (bytes + 255) & ~(size_t)255;
    return q;
  };
  float* xc   = (float*)alloc((size_t)N_C * H * 4);
  float* xt   = (float*)alloc((size_t)N_T * H * 4);
  float* xc_b = (float*)alloc((size_t)N_C * H * 4);
  float* xt_b = (float*)alloc((size_t)N_T * H * 4);
  unsigned short* xch   = (unsigned short*)alloc((size_t)N_C * H * 2);
  unsigned short* xth   = (unsigned short*)alloc((size_t)N_T * H * 2);
  unsigned short* xch_b = (unsigned short*)alloc((size_t)N_C * H * 2);
  unsigned short* xth_b = (unsigned short*)alloc((size_t)N_T * H * 2);
  __bf16* WcT = (__bf16*)alloc((size_t)D_C * H * 2);
  __bf16* WtT = (__bf16*)alloc((size_t)D_T * H * 2);
  __bf16* WsT = (__bf16*)alloc((size_t)6 * H * H * 2);
  int*    h1        = (int*)alloc((size_t)NB_TOT * CCH * 4);
  int*    b1        = (int*)alloc((size_t)NB_TOT * CCH * 4);
  int*    T         = (int*)alloc((size_t)NB_TOT * 4);
  uint32* packT_t   = (uint32*)alloc((size_t)E_EDGES * 4);
  uint32* packT_c   = (uint32*)alloc((size_t)E_EDGES * 4);
  int*    rowptr_t  = (int*)alloc((size_t)(N_T + 1) * 4);
  int*    rowptr_c  = (int*)alloc((size_t)(N_C + 1) * 4);
  int*    col_ct    = (int*)alloc((size_t)E_EDGES * 4);
  int*    col_tc    = (int*)alloc((size_t)E_EDGES * 4);

  // node 1: weight prep + zero bucket totals
  const int PREP_TOTAL = NB_TOT + D_C * 64 + D_T * 64 + 6 * 4096;
  prep_kernel<<<dim3((PREP_TOTAL + 255) / 256), dim3(256), 0, stream>>>(
      Wc, Wt, Wl_tc, Wr_tc, WcT, WtT, WsT, T);

  // node 2: both dense input projections
  proj_kernel<<<dim3(NBC + NBT), dim3(256), 0, stream>>>(
      x_comp, WcT, bc, xc, xch, x_tgt, WtT, bt, xt, xth);

  // nodes 3-6: CSR build (two-level counting sort)
  csr1_kernel<<<dim3(2 * CCH), dim3(256), 0, stream>>>(dst_ct, dst_tc, h1, T);
  csr2_kernel<<<dim3(NB_TOT), dim3(256), 0, stream>>>(h1, T, b1);
  csr3_kernel<<<dim3(2 * CCH), dim3(256), 0, stream>>>(
      src_ct, dst_ct, src_tc, dst_tc, b1, packT_t, packT_c);
  csr4_kernel<<<dim3(NB_TOT), dim3(256), 0, stream>>>(
      b1, packT_t, packT_c, rowptr_t, col_ct, rowptr_c, col_tc);

  // layers: 2 nodes per layer (layerT then layerC) for counter attribution
  float* xc_a = xc; float* xt_a = xt;
  float* xc_n = xc_b; float* xt_n = xt_b;
  unsigned short* xch_a = xch; unsigned short* xth_a = xth;
  unsigned short* xch_n = xch_b; unsigned short* xth_n = xth_b;
  for (int l = 0; l < NL; ++l) {
    layerT_kernel<<<dim3(N_T), dim3(256), 0, stream>>>(
        xch_a, xt_a, rowptr_t, col_ct,
        Wl_ct + (size_t)l * H * H, bl_ct + (size_t)l * H, Wr_ct + (size_t)l * H * H,
        xt_n, xth_n);
    layerC_kernel<<<dim3(NBC), dim3(256), 0, stream>>>(
        xch_a, xth_a, rowptr_c, col_tc,
        WsT + (size_t)l * H * H, WsT + (size_t)(3 + l) * H * H,
        bl_tc + (size_t)l * H, xc_a, xc_n, xch_n);
    float* t;
    t = xc_a; xc_a = xc_n; xc_n = t;
    t = xt_a; xt_a = xt_n; xt_n = t;
    unsigned short* th;
    th = xch_a; xch_a = xch_n; xch_n = th;
    th = xth_a; xth_a = xth_n; xth_n = th;
  }

  // final node: output head
  head_kernel<<<dim3((N_C + 3) / 4), dim3(256), 0, stream>>>(xc_a, Wo1, bo1, Wo2, bo2, out, N_C);
}

// Round 6
// 655.865 us; speedup vs baseline: 4.6448x; 1.0318x over previous
//
#include <hip/hip_runtime.h>

typedef unsigned int uint32;
typedef __bf16 bf16x8 __attribute__((ext_vector_type(8)));
typedef float f32x4 __attribute__((ext_vector_type(4)));

constexpr int N_C = 100000, N_T = 5000, E_EDGES = 2000000;
constexpr int D_C = 1024, D_T = 1280, H = 64, H2 = 32, NL = 3;
constexpr int PJC = (N_C + 63) / 64;     // 1563 proj blocks (64 rows/block)
constexpr int PJT = (N_T + 63) / 64;     // 79
constexpr int NBC64 = (N_C + 63) / 64;   // 1563 layerC blocks

// ---- CSR build (two-level counting sort, zero atomic-with-return) ----
constexpr int CCH = 200;                  // chunks per graph
constexpr int CHE = E_EDGES / CCH;        // 10000 edges per chunk (exact)
constexpr int SH_T = 4,  FB_T = 16;       // target: bucket = dst>>4, 16 fine bins
constexpr int SH_C = 8,  FB_C = 256;      // compound: bucket = dst>>8, 256 fine bins
constexpr int NB_T_B = (N_T + FB_T - 1) / FB_T;   // 313 buckets
constexpr int NB_C_B = (N_C + FB_C - 1) / FB_C;   // 391 buckets
constexpr int NB_TOT = NB_T_B + NB_C_B;           // 704
// packT entry: (dst<<SB)|src ; col output stores plain src
constexpr int PB_T = 17; constexpr uint32 PM_T = 0x1FFFFu;
constexpr int PB_C = 13; constexpr uint32 PM_C = 0x1FFFu;

__device__ inline unsigned short f2bf(float f) {
  uint32 u = __float_as_uint(f);
  u += 0x7fffu + ((u >> 16) & 1u);          // round-to-nearest-even
  return (unsigned short)(u >> 16);
}

// ---------------- prep: weight transposes + zero bucket totals (1 node)
__global__ __launch_bounds__(256) void prep_kernel(
    const float* __restrict__ Wc, const float* __restrict__ Wt,
    const float* __restrict__ Wl, const float* __restrict__ Wr,
    __bf16* __restrict__ WcT, __bf16* __restrict__ WtT, __bf16* __restrict__ WsT,
    int* __restrict__ T)
{
  int t = blockIdx.x * 256 + threadIdx.x;
  const int Z = NB_TOT;
  const int A = D_C * 64;
  const int B = D_T * 64;
  const int S = 6 * 64 * 64;
  if (t < Z) { T[t] = 0; return; }
  t -= Z;
  if (t < A) { int n = t & 63, k = t >> 6; WcT[(size_t)n * D_C + k] = (__bf16)Wc[(size_t)k * 64 + n]; return; }
  t -= A;
  if (t < B) { int n = t & 63, k = t >> 6; WtT[(size_t)n * D_T + k] = (__bf16)Wt[(size_t)k * 64 + n]; return; }
  t -= B;
  if (t < S) {
    int i = t >> 12;
    int r = t & 4095; int n = r & 63, k = r >> 6;
    const float* src = (i < 3) ? (Wl + (size_t)i * 4096) : (Wr + (size_t)(i - 3) * 4096);
    WsT[(size_t)i * 4096 + (size_t)n * 64 + k] = (__bf16)src[(size_t)k * 64 + n];
  }
}

// ---------------- MFMA projection body: y = relu(x @ W + b), 16 rows/wave, 2-deep prefetch
template<int K>
__device__ __forceinline__ void projM16_body(
    const float* __restrict__ x, const __bf16* __restrict__ WT,
    const float* __restrict__ b, float* __restrict__ y,
    unsigned short* __restrict__ yh, int n, int bidx)
{
  int w = threadIdx.x >> 6, l = threadIdx.x & 63;
  int lm = l & 15, lk = l >> 4;
  int base = bidx * 64 + w * 16;
  int r0 = base + lm; if (r0 >= n) r0 = n - 1;
  const float* xp0 = x + (size_t)r0 * K + lk * 8;
  const __bf16* wp = WT + (size_t)lm * K + lk * 8;

  f32x4 acc[4] = {{0,0,0,0},{0,0,0,0},{0,0,0,0},{0,0,0,0}};

  float4 p0 = *(const float4*)(xp0);
  float4 p1 = *(const float4*)(xp0 + 4);
  float4 q0 = *(const float4*)(xp0 + 32);
  float4 q1 = *(const float4*)(xp0 + 36);

  for (int k0 = 0; k0 < K; k0 += 32) {
    bf16x8 a0;
    a0[0]=(__bf16)p0.x; a0[1]=(__bf16)p0.y; a0[2]=(__bf16)p0.z; a0[3]=(__bf16)p0.w;
    a0[4]=(__bf16)p1.x; a0[5]=(__bf16)p1.y; a0[6]=(__bf16)p1.z; a0[7]=(__bf16)p1.w;
    p0 = q0; p1 = q1;
    if (k0 + 64 < K) {                      // 2-deep prefetch
      q0 = *(const float4*)(xp0 + k0 + 64);
      q1 = *(const float4*)(xp0 + k0 + 68);
    }
#pragma unroll
    for (int fn = 0; fn < 4; ++fn) {
      bf16x8 bv = *(const bf16x8*)(wp + (size_t)fn * 16 * K + k0);
      acc[fn] = __builtin_amdgcn_mfma_f32_16x16x32_bf16(a0, bv, acc[fn], 0, 0, 0);
    }
  }

#pragma unroll
  for (int fn = 0; fn < 4; ++fn) {
    int col = fn * 16 + lm;
    float bb = b[col];
#pragma unroll
    for (int reg = 0; reg < 4; ++reg) {
      int row = base + lk * 4 + reg;
      if (row < n) {
        float o = fmaxf(acc[fn][reg] + bb, 0.f);
        y[(size_t)row * 64 + col] = o;
        yh[(size_t)row * 64 + col] = f2bf(o);
      }
    }
  }
}

__global__ __launch_bounds__(256) void proj_kernel(
    const float* __restrict__ x_comp, const __bf16* __restrict__ WcT,
    const float* __restrict__ bc, float* __restrict__ xc, unsigned short* __restrict__ xch,
    const float* __restrict__ x_tgt, const __bf16* __restrict__ WtT,
    const float* __restrict__ bt, float* __restrict__ xt, unsigned short* __restrict__ xth)
{
  if (blockIdx.x < PJC) projM16_body<D_C>(x_comp, WcT, bc, xc, xch, N_C, blockIdx.x);
  else                  projM16_body<D_T>(x_tgt, WtT, bt, xt, xth, N_T, blockIdx.x - PJC);
}

// ---------------- csr1: per-chunk coarse-bucket histograms (LDS)
__global__ __launch_bounds__(256) void csr1_kernel(
    const int* __restrict__ dst_ct, const int* __restrict__ dst_tc,
    int* __restrict__ h1, int* __restrict__ T)
{
  __shared__ int hist[NB_C_B];
  int graph = (blockIdx.x >= CCH) ? 1 : 0;
  int chunk = graph ? (blockIdx.x - CCH) : blockIdx.x;
  const int* dst = graph ? dst_tc : dst_ct;
  int NB = graph ? NB_C_B : NB_T_B;
  int SH = graph ? SH_C : SH_T;
  for (int i = threadIdx.x; i < NB; i += 256) hist[i] = 0;
  __syncthreads();
  int e0 = chunk * CHE;
  for (int i = threadIdx.x; i < CHE; i += 256)
    atomicAdd(&hist[dst[e0 + i] >> SH], 1);
  __syncthreads();
  int* h1g = h1 + (graph ? (size_t)NB_T_B * CCH : 0);
  int* Tg  = T + (graph ? NB_T_B : 0);
  for (int i = threadIdx.x; i < NB; i += 256) {
    int v = hist[i];
    h1g[(size_t)i * CCH + chunk] = v;
    if (v) atomicAdd(&Tg[i], v);       // fire-and-forget
  }
}

// ---------------- csr2: per-bucket bases + chunk-prefix of h1 row
__global__ __launch_bounds__(256) void csr2_kernel(
    const int* __restrict__ h1, const int* __restrict__ T, int* __restrict__ b1)
{
  __shared__ int sh[256];
  __shared__ int loc2[512];
  int b = blockIdx.x;
  int graph = (b >= NB_T_B) ? 1 : 0;
  int nb = graph ? NB_C_B : NB_T_B;
  int base = graph ? NB_T_B : 0;
  int bl = b - base;
  int tid = threadIdx.x;
  int v0 = (2 * tid     < nb) ? T[base + 2 * tid]     : 0;
  int v1 = (2 * tid + 1 < nb) ? T[base + 2 * tid + 1] : 0;
  int t = v0 + v1;
  sh[tid] = t;
  __syncthreads();
  for (int off = 1; off < 256; off <<= 1) {
    int xv = (tid >= off) ? sh[tid - off] : 0;
    __syncthreads(); sh[tid] += xv; __syncthreads();
  }
  int excl = sh[tid] - t;
  loc2[2 * tid] = excl;
  loc2[2 * tid + 1] = excl + v0;
  __syncthreads();
  int B = loc2[bl];
  const int* row = h1 + (graph ? (size_t)NB_T_B * CCH : 0) + (size_t)bl * CCH;
  int hv = (tid < CCH) ? row[tid] : 0;
  sh[tid] = hv;
  __syncthreads();
  for (int off = 1; off < 256; off <<= 1) {
    int xv = (tid >= off) ? sh[tid - off] : 0;
    __syncthreads(); sh[tid] += xv; __syncthreads();
  }
  int e2 = sh[tid] - hv;
  if (tid < CCH) {
    int* b1g = b1 + (graph ? (size_t)NB_T_B * CCH : 0) + (size_t)bl * CCH;
    b1g[tid] = B + e2;
  }
}

// ---------------- csr3: scatter edges into bucket-major temp (packed)
__global__ __launch_bounds__(256) void csr3_kernel(
    const int* __restrict__ src_ct, const int* __restrict__ dst_ct,
    const int* __restrict__ src_tc, const int* __restrict__ dst_tc,
    const int* __restrict__ b1, uint32* __restrict__ packT_t, uint32* __restrict__ packT_c)
{
  __shared__ int cur[NB_C_B];
  int graph = (blockIdx.x >= CCH) ? 1 : 0;
  int chunk = graph ? (blockIdx.x - CCH) : blockIdx.x;
  const int* dst = graph ? dst_tc : dst_ct;
  const int* src = graph ? src_tc : src_ct;
  uint32* packT = graph ? packT_c : packT_t;
  int NB = graph ? NB_C_B : NB_T_B;
  int SH = graph ? SH_C : SH_T;
  int SB = graph ? PB_C : PB_T;
  const int* b1g = b1 + (graph ? (size_t)NB_T_B * CCH : 0);
  for (int i = threadIdx.x; i < NB; i += 256) cur[i] = b1g[(size_t)i * CCH + chunk];
  __syncthreads();
  int e0 = chunk * CHE;
  for (int i = threadIdx.x; i < CHE; i += 256) {
    int d = dst[e0 + i], s = src[e0 + i];
    int p = atomicAdd(&cur[d >> SH], 1);   // LDS atomic
    packT[p] = ((uint32)d << SB) | (uint32)s;
  }
}

// ---------------- csr4: per-bucket fine counting sort -> rowptr + col (plain src)
__global__ __launch_bounds__(256) void csr4_kernel(
    const int* __restrict__ b1, const uint32* __restrict__ packT_t,
    const uint32* __restrict__ packT_c,
    int* __restrict__ rowptr_t, int* __restrict__ col_ct,
    int* __restrict__ rowptr_c, int* __restrict__ col_tc)
{
  __shared__ int hist[FB_C];
  __shared__ int exc[256];
  int b = blockIdx.x;
  int graph = (b >= NB_T_B) ? 1 : 0;
  int bl = graph ? (b - NB_T_B) : b;
  int nb = graph ? NB_C_B : NB_T_B;
  int FB = graph ? FB_C : FB_T;
  int SB = graph ? PB_C : PB_T;
  uint32 SM = graph ? PM_C : PM_T;
  uint32 FMM = (uint32)(FB - 1);
  int N  = graph ? N_C : N_T;
  const uint32* packT = graph ? packT_c : packT_t;
  int* rowptr = graph ? rowptr_c : rowptr_t;
  int* col    = graph ? col_tc : col_ct;
  const int* b1g = b1 + (graph ? (size_t)NB_T_B * CCH : 0);
  int seg0 = b1g[(size_t)bl * CCH];
  int seg1 = (bl + 1 < nb) ? b1g[(size_t)(bl + 1) * CCH] : E_EDGES;
  int tid = threadIdx.x;
  if (tid < FB) hist[tid] = 0;
  __syncthreads();
  for (int i = seg0 + tid; i < seg1; i += 256)
    atomicAdd(&hist[(packT[i] >> SB) & FMM], 1);
  __syncthreads();
  int hv = (tid < FB) ? hist[tid] : 0;
  exc[tid] = hv;
  __syncthreads();
  for (int off = 1; off < 256; off <<= 1) {
    int xv = (tid >= off) ? exc[tid - off] : 0;
    __syncthreads(); exc[tid] += xv; __syncthreads();
  }
  int excl = exc[tid] - hv;
  __syncthreads();
  if (tid < FB) {
    int gbin = bl * FB + tid;
    if (gbin <= N) rowptr[gbin] = seg0 + excl;
    hist[tid] = seg0 + excl;
  }
  __syncthreads();
  for (int i = seg0 + tid; i < seg1; i += 256) {
    uint32 pk = packT[i];
    int p = atomicAdd(&hist[(pk >> SB) & FMM], 1);
    col[p] = (int)(pk & SM);                      // plain src index
  }
}

// ---------------- layerT: target-side SAGE, one block per row (masked batch gather)
__global__ __launch_bounds__(256) void layerT_kernel(
    const unsigned short* __restrict__ xch_a, const float* __restrict__ xt_a,
    const int* __restrict__ rowptr_t, const int* __restrict__ col_ct,
    const float* __restrict__ Wl_t, const float* __restrict__ bl_t, const float* __restrict__ Wr_t,
    float* __restrict__ xt_n, unsigned short* __restrict__ xth_n)
{
  __shared__ __align__(16) float part[4][64];
  __shared__ __align__(16) float opart[4][64];

  int l = threadIdx.x & 63, w = threadIdx.x >> 6;
  int d = l & 31, half = l >> 5;

  int r = blockIdx.x;
  int start = rowptr_t[r], end = rowptr_t[r + 1];
  int deg = end - start;
  int quarter = (deg + 3) >> 2;
  int js = start + w * quarter;
  int je = js + quarter; if (je > end) je = end;
  const uint32* xp = (const uint32*)xch_a;
  float a0 = 0.f, a1 = 0.f;
  int j0 = js + half;
  for (int j = j0; j < je; j += 16) {      // 8 masked edges per half per batch
    int idx[8]; uint32 vv[8];
#pragma unroll
    for (int k = 0; k < 8; ++k) {
      int jj = j + 2 * k;
      idx[k] = col_ct[(jj < je) ? jj : j];
    }
#pragma unroll
    for (int k = 0; k < 8; ++k) vv[k] = xp[(size_t)idx[k] * 32 + d];
#pragma unroll
    for (int k = 0; k < 8; ++k) {
      bool m = (j + 2 * k) < je;
      a0 += m ? __uint_as_float(vv[k] << 16) : 0.f;
      a1 += m ? __uint_as_float(vv[k] & 0xffff0000u) : 0.f;
    }
  }
  a0 += __shfl_xor(a0, 32, 64);
  a1 += __shfl_xor(a1, 32, 64);
  if (half == 0) *(float2*)&part[w][2 * d] = make_float2(a0, a1);
  __syncthreads();
  float m = (part[0][l] + part[1][l] + part[2][l] + part[3][l])
            * ((deg > 0) ? (1.0f / (float)deg) : 0.f);
  float xv = xt_a[(size_t)r * 64 + l];
  float o = 0.f;
  int k0 = w * 16;
#pragma unroll
  for (int kk = 0; kk < 16; ++kk) {
    int k = k0 + kk;
    float mk = __uint_as_float(__builtin_amdgcn_readlane(__float_as_uint(m), k));
    float xk = __uint_as_float(__builtin_amdgcn_readlane(__float_as_uint(xv), k));
    o = fmaf(mk, Wl_t[k * 64 + l], o);
    o = fmaf(xk, Wr_t[k * 64 + l], o);
  }
  opart[w][l] = o;
  __syncthreads();
  if (w == 0) {
    float oo = opart[0][l] + opart[1][l] + opart[2][l] + opart[3][l] + bl_t[l];
    float res = fmaxf(oo, 0.f) + xv;
    xt_n[(size_t)r * 64 + l] = res;
    xth_n[(size_t)r * 64 + l] = f2bf(res);
  }
}

// ---------------- layerC: 64 rows/block (16/wave) reg-acc agg + MFMA combine
__global__ __launch_bounds__(256) void layerC_kernel(
    const unsigned short* __restrict__ xch_a,
    const unsigned short* __restrict__ xth_a, const int* __restrict__ rowptr_c,
    const int* __restrict__ col_tc,
    const __bf16* __restrict__ WlT, const __bf16* __restrict__ WrT,
    const float* __restrict__ bl_c, const float* __restrict__ xc_a,
    float* __restrict__ xc_n, unsigned short* __restrict__ xch_n)
{
  __shared__ __align__(16) uint32 smem_u[64 * 36];   // 9.2 KB packed bf16 means

  int l = threadIdx.x & 63, w = threadIdx.x >> 6;
  int d = l & 31, half = l >> 5;

  int bbase = blockIdx.x * 64;

  int rp_idx = bbase + w * 16 + ((l <= 16) ? l : 16);
  if (rp_idx > N_C) rp_idx = N_C;
  int rpl = rowptr_c[rp_idx];
  const uint32* xp = (const uint32*)xth_a;

#pragma unroll 1
  for (int t = 0; t < 8; ++t) {
    int s = __shfl(rpl, 2 * t + half, 64);
    int e = __shfl(rpl, 2 * t + half + 1, 64);
    float a0 = 0.f, a1 = 0.f;
    int n = e - s;
    for (int j = 0; j < n; j += 8) {       // masked batch of 8, no serial tail
      int idx[8]; uint32 vv[8];
#pragma unroll
      for (int k = 0; k < 8; ++k) {
        int jj = s + j + k;
        idx[k] = col_tc[(jj < e) ? jj : s];
      }
#pragma unroll
      for (int k = 0; k < 8; ++k) vv[k] = xp[(size_t)idx[k] * 32 + d];
#pragma unroll
      for (int k = 0; k < 8; ++k) {
        bool m = (j + k) < n;
        a0 += m ? __uint_as_float(vv[k] << 16) : 0.f;
        a1 += m ? __uint_as_float(vv[k] & 0xffff0000u) : 0.f;
      }
    }
    float inv = (n > 0) ? (1.0f / (float)n) : 0.f;
    uint32 packed = (uint32)f2bf(a0 * inv) | ((uint32)f2bf(a1 * inv) << 16);
    smem_u[(size_t)(w * 16 + 2 * t + half) * 36 + d] = packed;
  }
  __syncthreads();

  // MFMA combine: xnew = relu(mean@Wl + X@Wr + bl) + X   (16 rows/wave)
  int lm = l & 15, lk = l >> 4;
  int base = bbase + w * 16;
  int r0 = base + lm; if (r0 >= N_C) r0 = N_C - 1;
  const unsigned short* x0 = xch_a + (size_t)r0 * 64 + lk * 8;
  const __bf16* wl = WlT + (size_t)lm * 64 + lk * 8;
  const __bf16* wr = WrT + (size_t)lm * 64 + lk * 8;

  f32x4 acc[4] = {{0,0,0,0},{0,0,0,0},{0,0,0,0},{0,0,0,0}};

#pragma unroll
  for (int ks = 0; ks < 64; ks += 32) {
    bf16x8 am0 = *(const bf16x8*)&smem_u[(size_t)(w * 16 + lm) * 36 + lk * 4 + (ks >> 1)];
    bf16x8 ax0 = *(const bf16x8*)(x0 + ks);
#pragma unroll
    for (int fn = 0; fn < 4; ++fn) {
      bf16x8 bl_v = *(const bf16x8*)(wl + (size_t)fn * 16 * 64 + ks);
      bf16x8 br_v = *(const bf16x8*)(wr + (size_t)fn * 16 * 64 + ks);
      acc[fn] = __builtin_amdgcn_mfma_f32_16x16x32_bf16(am0, bl_v, acc[fn], 0, 0, 0);
      acc[fn] = __builtin_amdgcn_mfma_f32_16x16x32_bf16(ax0, br_v, acc[fn], 0, 0, 0);
    }
  }

#pragma unroll
  for (int fn = 0; fn < 4; ++fn) {
    int col = fn * 16 + lm;
    float bb = bl_c[col];
#pragma unroll
    for (int reg = 0; reg < 4; ++reg) {
      int row = base + lk * 4 + reg;
      if (row < N_C) {
        float xv = xc_a[(size_t)row * 64 + col];
        float o = fmaxf(acc[fn][reg] + bb, 0.f) + xv;
        xc_n[(size_t)row * 64 + col] = o;
        xch_n[(size_t)row * 64 + col] = f2bf(o);
      }
    }
  }
}

// ---------------- head: out[r] = relu(xc[r] @ Wo1 + bo1) @ Wo2 + bo2
__global__ __launch_bounds__(256) void head_kernel(
    const float* __restrict__ xc, const float* __restrict__ Wo1,
    const float* __restrict__ bo1, const float* __restrict__ Wo2,
    const float* __restrict__ bo2, float* __restrict__ out, int n)
{
  int lane = threadIdx.x & 63;
  int wid = blockIdx.x * (blockDim.x >> 6) + (threadIdx.x >> 6);
  if (wid >= n) return;
  float xv = xc[(size_t)wid * 64 + lane];
  float h = (lane < H2) ? bo1[lane] : 0.f;
  const float* wcol = Wo1 + ((lane < H2) ? lane : 0);
#pragma unroll 8
  for (int k = 0; k < 64; ++k) {
    float xk = __uint_as_float(__builtin_amdgcn_readlane(__float_as_uint(xv), k));
    h = fmaf(xk, wcol[k * H2], h);
  }
  float v = (lane < H2) ? fmaxf(h, 0.f) * Wo2[lane] : 0.f;
#pragma unroll
  for (int off = 32; off > 0; off >>= 1) v += __shfl_down(v, off, 64);
  if (lane == 0) out[wid] = v + bo2[0];
}

extern "C" void kernel_launch(void* const* d_in, const int* in_sizes, int n_in,
                              void* d_out, int out_size, void* d_ws, size_t ws_size,
                              hipStream_t stream)
{
  const float* x_comp = (const float*)d_in[0];
  const float* x_tgt  = (const float*)d_in[1];
  const int*   src_ct = (const int*)d_in[2];
  const int*   dst_ct = (const int*)d_in[3];
  const int*   src_tc = (const int*)d_in[4];
  const int*   dst_tc = (const int*)d_in[5];
  const float* Wc    = (const float*)d_in[6];
  const float* bc    = (const float*)d_in[7];
  const float* Wt    = (const float*)d_in[8];
  const float* bt    = (const float*)d_in[9];
  const float* Wl_ct = (const float*)d_in[10];
  const float* bl_ct = (const float*)d_in[11];
  const float* Wr_ct = (const float*)d_in[12];
  const float* Wl_tc = (const float*)d_in[13];
  const float* bl_tc = (const float*)d_in[14];
  const float* Wr_tc = (const float*)d_in[15];
  const float* Wo1   = (const float*)d_in[16];
  const float* bo1   = (const float*)d_in[17];
  const float* Wo2   = (const float*)d_in[18];
  const float* bo2   = (const float*)d_in[19];
  float* out = (float*)d_out;

  char* p = (char*)d_ws;
  auto alloc = [&](size_t bytes) {
    char* q = p;
    p += (bytes + 255) & ~(size_t)255;
    return q;
  };
  float* xc   = (float*)alloc((size_t)N_C * H * 4);
  float* xt   = (float*)alloc((size_t)N_T * H * 4);
  float* xc_b = (float*)alloc((size_t)N_C * H * 4);
  float* xt_b = (float*)alloc((size_t)N_T * H * 4);
  unsigned short* xch   = (unsigned short*)alloc((size_t)N_C * H * 2);
  unsigned short* xth   = (unsigned short*)alloc((size_t)N_T * H * 2);
  unsigned short* xch_b = (unsigned short*)alloc((size_t)N_C * H * 2);
  unsigned short* xth_b = (unsigned short*)alloc((size_t)N_T * H * 2);
  __bf16* WcT = (__bf16*)alloc((size_t)D_C * H * 2);
  __bf16* WtT = (__bf16*)alloc((size_t)D_T * H * 2);
  __bf16* WsT = (__bf16*)alloc((size_t)6 * H * H * 2);
  int*    h1        = (int*)alloc((size_t)NB_TOT * CCH * 4);
  int*    b1        = (int*)alloc((size_t)NB_TOT * CCH * 4);
  int*    T         = (int*)alloc((size_t)NB_TOT * 4);
  uint32* packT_t   = (uint32*)alloc((size_t)E_EDGES * 4);
  uint32* packT_c   = (uint32*)alloc((size_t)E_EDGES * 4);
  int*    rowptr_t  = (int*)alloc((size_t)(N_T + 1) * 4);
  int*    rowptr_c  = (int*)alloc((size_t)(N_C + 1) * 4);
  int*    col_ct    = (int*)alloc((size_t)E_EDGES * 4);
  int*    col_tc    = (int*)alloc((size_t)E_EDGES * 4);

  // node 1: weight prep + zero bucket totals
  const int PREP_TOTAL = NB_TOT + D_C * 64 + D_T * 64 + 6 * 4096;
  prep_kernel<<<dim3((PREP_TOTAL + 255) / 256), dim3(256), 0, stream>>>(
      Wc, Wt, Wl_tc, Wr_tc, WcT, WtT, WsT, T);

  // node 2: both dense input projections (16 rows/wave, 2-deep prefetch)
  proj_kernel<<<dim3(PJC + PJT), dim3(256), 0, stream>>>(
      x_comp, WcT, bc, xc, xch, x_tgt, WtT, bt, xt, xth);

  // nodes 3-6: CSR build (two-level counting sort)
  csr1_kernel<<<dim3(2 * CCH), dim3(256), 0, stream>>>(dst_ct, dst_tc, h1, T);
  csr2_kernel<<<dim3(NB_TOT), dim3(256), 0, stream>>>(h1, T, b1);
  csr3_kernel<<<dim3(2 * CCH), dim3(256), 0, stream>>>(
      src_ct, dst_ct, src_tc, dst_tc, b1, packT_t, packT_c);
  csr4_kernel<<<dim3(NB_TOT), dim3(256), 0, stream>>>(
      b1, packT_t, packT_c, rowptr_t, col_ct, rowptr_c, col_tc);

  // layers: 2 nodes per layer (layerT then layerC)
  float* xc_a = xc; float* xt_a = xt;
  float* xc_n = xc_b; float* xt_n = xt_b;
  unsigned short* xch_a = xch; unsigned short* xth_a = xth;
  unsigned short* xch_n = xch_b; unsigned short* xth_n = xth_b;
  for (int l = 0; l < NL; ++l) {
    layerT_kernel<<<dim3(N_T), dim3(256), 0, stream>>>(
        xch_a, xt_a, rowptr_t, col_ct,
        Wl_ct + (size_t)l * H * H, bl_ct + (size_t)l * H, Wr_ct + (size_t)l * H * H,
        xt_n, xth_n);
    layerC_kernel<<<dim3(NBC64), dim3(256), 0, stream>>>(
        xch_a, xth_a, rowptr_c, col_tc,
        WsT + (size_t)l * H * H, WsT + (size_t)(3 + l) * H * H,
        bl_tc + (size_t)l * H, xc_a, xc_n, xch_n);
    float* t;
    t = xc_a; xc_a = xc_n; xc_n = t;
    t = xt_a; xt_a = xt_n; xt_n = t;
    unsigned short* th;
    th = xch_a; xch_a = xch_n; xch_n = th;
    th = xth_a; xth_a = xth_n; xth_n = th;
  }

  // final node: output head
  head_kernel<<<dim3((N_C + 3) / 4), dim3(256), 0, stream>>>(xc_a, Wo1, bo1, Wo2, bo2, out, N_C);
}